// Round 4
// baseline (80.906 us; speedup 1.0000x reference)
//
#include <hip/hip_runtime.h>
#include <math.h>

#define QN 8192
#define AN 2048
#define DN 64
#define AS2 44          // floats per atom record (11 float4)
#define NFIELDS 11
#define NQ 4            // queries per thread in splat_partial

#define SQ2f      1.4142135623730951f
#define INV_SQ2f  0.7071067811865476f
#define SQ6_INVf  0.4082482904638631f
#define LOG2Ef    1.4426950408889634f

__device__ __forceinline__ float wave_sum(float v) {
#pragma unroll
  for (int off = 32; off > 0; off >>= 1) v += __shfl_xor(v, off, 64);
  return v;
}

// ---------------- Kernel A: per-atom precompute ----------------
// record[a][0..43] (11 float4):
//  v0: ax, ay, az, -alpha*log2e
//  v1: c0e(+b0), c0o(+b1), dipx(+b2), dipy
//  v2: dipz, bivx(+b3), bivy, bivz
//  v3: Qxx,Qxy,Qxz,Qyy   v4: Qyz,Qzz,Oxx,Oxy   v5: Oxz,Oyy,Oyz,Ozz
//  v6: le_x,le_y,le_z,lo_x   v7: lo_y,lo_z,qe_xx,qe_yy   v8: qe_zz,qe_xy,qe_xz,qe_yz
//  v9: qo_xx,qo_yy,qo_zz,qo_xy   v10: qo_xz,qo_yz,0,0
__global__ __launch_bounds__(256) void precompute_atoms(
    const float* __restrict__ atom_coords, const float* __restrict__ alpha,
    const float* __restrict__ even_scalar, const float* __restrict__ odd_scalar,
    const float* __restrict__ odd_vector, const float* __restrict__ even_vector,
    const float* __restrict__ even_tensor, const float* __restrict__ odd_tensor,
    const float* __restrict__ W, const float* __restrict__ b,
    float* __restrict__ out)
{
  const int a = blockIdx.x * 4 + (threadIdx.x >> 6);
  const int d = threadIdx.x & 63;

  const float es  = even_scalar[a * DN + d];
  const float os  = odd_scalar[a * DN + d];
  const float ov0 = odd_vector[(a * DN + d) * 3 + 0];
  const float ov1 = odd_vector[(a * DN + d) * 3 + 1];
  const float ov2 = odd_vector[(a * DN + d) * 3 + 2];
  const float ev0 = even_vector[(a * DN + d) * 3 + 0];
  const float ev1 = even_vector[(a * DN + d) * 3 + 1];
  const float ev2 = even_vector[(a * DN + d) * 3 + 2];
  const float et0 = even_tensor[(a * DN + d) * 5 + 0];
  const float et1 = even_tensor[(a * DN + d) * 5 + 1];
  const float et2 = even_tensor[(a * DN + d) * 5 + 2];
  const float et3 = even_tensor[(a * DN + d) * 5 + 3];
  const float et4 = even_tensor[(a * DN + d) * 5 + 4];
  const float ot0 = odd_tensor[(a * DN + d) * 5 + 0];
  const float ot1 = odd_tensor[(a * DN + d) * 5 + 1];
  const float ot2 = odd_tensor[(a * DN + d) * 5 + 2];
  const float ot3 = odd_tensor[(a * DN + d) * 5 + 3];
  const float ot4 = odd_tensor[(a * DN + d) * 5 + 4];

  const float w0 = W[0 * DN + d];
  const float w1 = W[1 * DN + d];
  const float w2 = W[2 * DN + d];
  const float w3 = W[3 * DN + d];
  const float w4 = W[4 * DN + d];
  const float w5 = W[5 * DN + d];
  const float w6 = W[6 * DN + d];
  const float w7 = W[7 * DN + d];
  const float w8 = W[8 * DN + d];
  const float w9 = W[9 * DN + d];

  float r[34];
  r[0]  = es * w0;
  r[1]  = os * w1;
  r[2]  = ov0 * w2; r[3]  = ov1 * w2; r[4]  = ov2 * w2;
  r[5]  = ev0 * w3; r[6]  = ev1 * w3; r[7]  = ev2 * w3;
  r[8]  = et0 * w4; r[9]  = et1 * w4; r[10] = et2 * w4; r[11] = et3 * w4; r[12] = et4 * w4;
  r[13] = ot0 * w5; r[14] = ot1 * w5; r[15] = ot2 * w5; r[16] = ot3 * w5; r[17] = ot4 * w5;
  r[18] = ov0 * w6; r[19] = ov1 * w6; r[20] = ov2 * w6;
  r[21] = ev0 * w7; r[22] = ev1 * w7; r[23] = ev2 * w7;
  r[24] = et0 * w8; r[25] = et1 * w8; r[26] = et2 * w8; r[27] = et3 * w8; r[28] = et4 * w8;
  r[29] = ot0 * w9; r[30] = ot1 * w9; r[31] = ot2 * w9; r[32] = ot3 * w9; r[33] = ot4 * w9;

#pragma unroll
  for (int k = 0; k < 34; ++k) r[k] = wave_sum(r[k]);

  if (d == 0) {
    float* o = out + (size_t)a * AS2;
    o[0] = atom_coords[a * 3 + 0];
    o[1] = atom_coords[a * 3 + 1];
    o[2] = atom_coords[a * 3 + 2];
    o[3] = -alpha[a] * LOG2Ef;
    o[4] = r[0] + b[0];
    o[5] = r[1] + b[1];
    o[6] = r[2] + b[2]; o[7] = r[3] + b[2]; o[8] = r[4] + b[2];
    o[9] = r[5] + b[3]; o[10] = r[6] + b[3]; o[11] = r[7] + b[3];
    {
      float c0 = r[8] + b[4], c1 = r[9] + b[4], c2 = r[10] + b[4],
            c3 = r[11] + b[4], c4 = r[12] + b[4];
      float zz = c1 * 0.816496580927726f;
      float xx = 0.5f * (c0 * SQ2f - zz);
      float yy = 0.5f * (-c0 * SQ2f - zz);
      float xy = c2 * INV_SQ2f, xz = c3 * INV_SQ2f, yz = c4 * INV_SQ2f;
      o[12] = xx; o[13] = xy; o[14] = xz; o[15] = yy; o[16] = yz; o[17] = zz;
    }
    {
      float c0 = r[13] + b[5], c1 = r[14] + b[5], c2 = r[15] + b[5],
            c3 = r[16] + b[5], c4 = r[17] + b[5];
      float zz = c1 * 0.816496580927726f;
      float xx = 0.5f * (c0 * SQ2f - zz);
      float yy = 0.5f * (-c0 * SQ2f - zz);
      float xy = c2 * INV_SQ2f, xz = c3 * INV_SQ2f, yz = c4 * INV_SQ2f;
      o[18] = xx; o[19] = xy; o[20] = xz; o[21] = yy; o[22] = yz; o[23] = zz;
    }
    o[24] = r[18]; o[25] = r[19]; o[26] = r[20];     // le
    o[27] = r[21]; o[28] = r[22]; o[29] = r[23];     // lo
    {
      float A0 = r[24] * INV_SQ2f, A1 = r[25] * SQ6_INVf;
      float A2 = r[26] * SQ2f, A3 = r[27] * SQ2f, A4 = r[28] * SQ2f;
      o[30] = A0 - A1; o[31] = -A0 - A1; o[32] = 2.0f * A1;
      o[33] = A2; o[34] = A3; o[35] = A4;
    }
    {
      float A0 = r[29] * INV_SQ2f, A1 = r[30] * SQ6_INVf;
      float A2 = r[31] * SQ2f, A3 = r[32] * SQ2f, A4 = r[33] * SQ2f;
      o[36] = A0 - A1; o[37] = -A0 - A1; o[38] = 2.0f * A1;
      o[39] = A2; o[40] = A3; o[41] = A4;
    }
    o[42] = 0.f; o[43] = 0.f;
  }
}

// ---------------- Kernel B: pair loop, NQ queries/thread, LDS-staged atoms ---
// P layout: P[(s*NFIELDS + f)*QN + q]
__global__ __launch_bounds__(256, 4) void splat_partial(
    const float* __restrict__ qcoord, const float* __restrict__ ad,
    float* __restrict__ P, int chunk)
{
  extern __shared__ float4 sm[];   // chunk * 11 float4
  const int tid = threadIdx.x;
  const int qbase = blockIdx.x * (256 * NQ) + tid;
  const int s = blockIdx.y;

  // stage this block's atom chunk into LDS (coalesced)
  {
    const float4* src = (const float4*)(ad + (size_t)(s * chunk) * AS2);
    const int n4 = chunk * 11;
    for (int t = tid; t < n4; t += 256) sm[t] = src[t];
  }

  float qx[NQ], qy[NQ], qz[NQ];
#pragma unroll
  for (int j = 0; j < NQ; ++j) {
    const int q = qbase + j * 256;
    qx[j] = qcoord[q * 3 + 0];
    qy[j] = qcoord[q * 3 + 1];
    qz[j] = qcoord[q * 3 + 2];
  }
  __syncthreads();

  float Sw[NQ], Se[NQ], So[NQ];
  float Svx[NQ], Svy[NQ], Svz[NQ];
  float Sbx[NQ], Sby[NQ], Sbz[NQ];
  float Sea[NQ], Soa[NQ];
#pragma unroll
  for (int j = 0; j < NQ; ++j) {
    Sw[j] = Se[j] = So[j] = 0.f;
    Svx[j] = Svy[j] = Svz[j] = 0.f;
    Sbx[j] = Sby[j] = Sbz[j] = 0.f;
    Sea[j] = Soa[j] = 0.f;
  }

  for (int i = 0; i < chunk; ++i) {
    const float4* c = sm + i * 11;
    const float4 c0 = c[0], c1 = c[1], c2 = c[2], c3 = c[3], c4 = c[4],
                 c5 = c[5], c6 = c[6], c7 = c[7], c8 = c[8], c9 = c[9],
                 c10 = c[10];
#pragma unroll
    for (int j = 0; j < NQ; ++j) {
      const float dx = qx[j] - c0.x, dy = qy[j] - c0.y, dz = qz[j] - c0.z;
      const float d2 = fmaf(dx, dx, fmaf(dy, dy, dz * dz));
      const float w = __builtin_amdgcn_exp2f(c0.w * d2);   // c0.w = -alpha*log2e
      const float inv = __builtin_amdgcn_rsqf(d2);
      const float inv2 = inv * inv;
      const float g1 = w * inv, g2 = w * inv2;

      Sw[j] += w;
      Se[j] = fmaf(w, c1.x, Se[j]); So[j] = fmaf(w, c1.y, So[j]);
      Svx[j] = fmaf(w, c1.z, Svx[j]); Svy[j] = fmaf(w, c1.w, Svy[j]);
      Svz[j] = fmaf(w, c2.x, Svz[j]);
      Sbx[j] = fmaf(w, c2.y, Sbx[j]); Sby[j] = fmaf(w, c2.z, Sby[j]);
      Sbz[j] = fmaf(w, c2.w, Sbz[j]);

      const float wdx = g1 * dx, wdy = g1 * dy, wdz = g1 * dz;
      Svx[j] = fmaf(c3.x, wdx, fmaf(c3.y, wdy, fmaf(c3.z, wdz, Svx[j])));
      Svy[j] = fmaf(c3.y, wdx, fmaf(c3.w, wdy, fmaf(c4.x, wdz, Svy[j])));
      Svz[j] = fmaf(c3.z, wdx, fmaf(c4.x, wdy, fmaf(c4.y, wdz, Svz[j])));
      Sbx[j] = fmaf(c4.z, wdx, fmaf(c4.w, wdy, fmaf(c5.x, wdz, Sbx[j])));
      Sby[j] = fmaf(c4.w, wdx, fmaf(c5.y, wdy, fmaf(c5.z, wdz, Sby[j])));
      Sbz[j] = fmaf(c5.x, wdx, fmaf(c5.z, wdy, fmaf(c5.w, wdz, Sbz[j])));

      const float xx = dx * dx, yy = dy * dy, zz = dz * dz;
      const float xy = dx * dy, xz = dx * dz, yz = dy * dz;
      const float lin_e = fmaf(dx, c6.x, fmaf(dy, c6.y, dz * c6.z));
      const float qd_e  = fmaf(xx, c7.z, fmaf(yy, c7.w, fmaf(zz, c8.x,
                          fmaf(xy, c8.y, fmaf(xz, c8.z, yz * c8.w)))));
      Sea[j] = fmaf(g1, lin_e, fmaf(g2, qd_e, Sea[j]));
      const float lin_o = fmaf(dx, c6.w, fmaf(dy, c7.x, dz * c7.y));
      const float qd_o  = fmaf(xx, c9.x, fmaf(yy, c9.y, fmaf(zz, c9.z,
                          fmaf(xy, c9.w, fmaf(xz, c10.x, yz * c10.y)))));
      Soa[j] = fmaf(g1, lin_o, fmaf(g2, qd_o, Soa[j]));
    }
  }

  float* Pb = P + (size_t)s * NFIELDS * QN;
#pragma unroll
  for (int j = 0; j < NQ; ++j) {
    const int q = qbase + j * 256;
    Pb[0 * QN + q]  = Sw[j];
    Pb[1 * QN + q]  = Se[j];
    Pb[2 * QN + q]  = So[j];
    Pb[3 * QN + q]  = Svx[j]; Pb[4 * QN + q]  = Svy[j]; Pb[5 * QN + q]  = Svz[j];
    Pb[6 * QN + q]  = Sbx[j]; Pb[7 * QN + q]  = Sby[j]; Pb[8 * QN + q]  = Sbz[j];
    Pb[9 * QN + q]  = Sea[j];
    Pb[10 * QN + q] = Soa[j];
  }
}

// ---------------- Kernel C1: reduce split partials, one field per block.y ----
__global__ __launch_bounds__(256) void reduce_splits(
    const float* __restrict__ P, float* __restrict__ F, int nsplit)
{
  const int q = blockIdx.x * 256 + threadIdx.x;
  const int f = blockIdx.y;
  float acc = 0.f;
  for (int s = 0; s < nsplit; ++s)
    acc += P[((size_t)s * NFIELDS + f) * QN + q];
  F[(size_t)f * QN + q] = acc;
}

// ---------------- Kernel C2: finalize outputs from F[11][QN] ----------------
__global__ __launch_bounds__(256) void combine(
    const float* __restrict__ F, const float* __restrict__ b,
    float* __restrict__ out)
{
  const int q = blockIdx.x * 256 + threadIdx.x;
  float acc[NFIELDS];
#pragma unroll
  for (int f = 0; f < NFIELDS; ++f) acc[f] = F[(size_t)f * QN + q];

  const float b_ea = b[6] + b[8];
  const float b_oa = b[7] + b[9];

  const float Sw = fmaxf(acc[0], 1e-8f);
  const float inv = 1.0f / Sw;
  const float snw = acc[0] * inv;             // == 1 unless clamped
  const float scal = acc[1] * inv;
  const float pse  = acc[2] * inv;
  const float vx = acc[3] * inv;
  const float vy = acc[4] * inv;
  const float vz = acc[5] * inv;
  const float bx = acc[6] * inv;
  const float by = acc[7] * inv;
  const float bz = acc[8] * inv;
  const float ea = fmaf(b_ea, snw, acc[9] * inv);
  const float oa = fmaf(b_oa, snw, acc[10] * inv);

  const float evenc = scal + ea;
  const float oddc  = pse + oa;
  const float vn = sqrtf(fmaf(vx, vx, fmaf(vy, vy, vz * vz)));
  const float bn = sqrtf(fmaf(bx, bx, fmaf(by, by, bz * bz)));
  const float total = evenc + oddc + 0.1f * vn + 0.05f * bn;

  out[q] = total;
  out[QN + q] = evenc;
  out[2 * QN + q] = oddc;
  float* mv = out + 3 * QN + (size_t)q * 16;
  mv[0] = scal;
  mv[1] = vx; mv[2] = vy; mv[3] = vz;
  mv[4] = 0.f;
  mv[5] = bz; mv[6] = -by; mv[7] = bx;
  mv[8] = 0.f; mv[9] = 0.f; mv[10] = 0.f;
  mv[11] = pse;
  mv[12] = 0.f; mv[13] = 0.f; mv[14] = 0.f; mv[15] = 0.f;
}

extern "C" void kernel_launch(void* const* d_in, const int* in_sizes, int n_in,
                              void* d_out, int out_size, void* d_ws, size_t ws_size,
                              hipStream_t stream) {
  const float* query_coords = (const float*)d_in[0];
  const float* atom_coords  = (const float*)d_in[1];
  const float* alpha        = (const float*)d_in[2];
  const float* even_scalar  = (const float*)d_in[3];
  const float* odd_scalar   = (const float*)d_in[4];
  const float* odd_vector   = (const float*)d_in[5];
  const float* even_vector  = (const float*)d_in[6];
  const float* even_tensor  = (const float*)d_in[7];
  const float* odd_tensor   = (const float*)d_in[8];
  const float* W            = (const float*)d_in[9];
  const float* b            = (const float*)d_in[10];
  float* out = (float*)d_out;

  const size_t adBytes = (size_t)AN * AS2 * sizeof(float);
  const size_t fBytes  = (size_t)NFIELDS * QN * sizeof(float);
  float* ad = (float*)d_ws;
  float* F  = (float*)((char*)d_ws + adBytes);
  float* P  = (float*)((char*)d_ws + adBytes + fBytes);

  int nsplit = 128;
  while (nsplit > 1 &&
         adBytes + fBytes + (size_t)nsplit * NFIELDS * QN * sizeof(float) > ws_size)
    nsplit >>= 1;
  const int chunk = AN / nsplit;
  const size_t smBytes = (size_t)chunk * 11 * sizeof(float4);

  precompute_atoms<<<AN / 4, 256, 0, stream>>>(
      atom_coords, alpha, even_scalar, odd_scalar, odd_vector, even_vector,
      even_tensor, odd_tensor, W, b, ad);
  splat_partial<<<dim3(QN / (256 * NQ), nsplit), 256, smBytes, stream>>>(
      query_coords, ad, P, chunk);
  reduce_splits<<<dim3(QN / 256, NFIELDS), 256, 0, stream>>>(P, F, nsplit);
  combine<<<QN / 256, 256, 0, stream>>>(F, b, out);
}

// Round 5
// 71.772 us; speedup vs baseline: 1.1273x; 1.1273x over previous
//
#include <hip/hip_runtime.h>
#include <math.h>

#define QN 8192
#define AN 2048
#define DN 64
#define AS2 44          // floats per atom record
#define NSPLIT 32
#define CHUNK 64        // atoms per block in mfma_splat

#define SQ2f      1.4142135623730951f
#define INV_SQ2f  0.7071067811865476f
#define SQ6_INVf  0.4082482904638631f
#define LOG2Ef    1.4426950408889634f

typedef __attribute__((ext_vector_type(8))) _Float16 half8;
typedef __attribute__((ext_vector_type(4))) float f32x4;

__device__ __forceinline__ float wave_sum(float v) {
#pragma unroll
  for (int off = 32; off > 0; off >>= 1) v += __shfl_xor(v, off, 64);
  return v;
}

// ---------------- Kernel A: per-atom precompute (f32 record, proven) --------
// o[0..43]: 0-2 coords, 3 -alpha*log2e, 4 c0e, 5 c0o, 6-8 dip, 9-11 biv,
//  12-17 Q sym [xx,xy,xz,yy,yz,zz], 18-23 O sym, 24-26 le, 27-29 lo,
//  30-35 even-ang quad coeffs on (xx,yy,zz,xy,xz,yz) of unit dir (cross pre-doubled),
//  36-41 odd-ang quad coeffs.
__global__ __launch_bounds__(256) void precompute_atoms(
    const float* __restrict__ atom_coords, const float* __restrict__ alpha,
    const float* __restrict__ even_scalar, const float* __restrict__ odd_scalar,
    const float* __restrict__ odd_vector, const float* __restrict__ even_vector,
    const float* __restrict__ even_tensor, const float* __restrict__ odd_tensor,
    const float* __restrict__ W, const float* __restrict__ b,
    float* __restrict__ out)
{
  const int a = blockIdx.x * 4 + (threadIdx.x >> 6);
  const int d = threadIdx.x & 63;

  const float es  = even_scalar[a * DN + d];
  const float os  = odd_scalar[a * DN + d];
  const float ov0 = odd_vector[(a * DN + d) * 3 + 0];
  const float ov1 = odd_vector[(a * DN + d) * 3 + 1];
  const float ov2 = odd_vector[(a * DN + d) * 3 + 2];
  const float ev0 = even_vector[(a * DN + d) * 3 + 0];
  const float ev1 = even_vector[(a * DN + d) * 3 + 1];
  const float ev2 = even_vector[(a * DN + d) * 3 + 2];
  const float et0 = even_tensor[(a * DN + d) * 5 + 0];
  const float et1 = even_tensor[(a * DN + d) * 5 + 1];
  const float et2 = even_tensor[(a * DN + d) * 5 + 2];
  const float et3 = even_tensor[(a * DN + d) * 5 + 3];
  const float et4 = even_tensor[(a * DN + d) * 5 + 4];
  const float ot0 = odd_tensor[(a * DN + d) * 5 + 0];
  const float ot1 = odd_tensor[(a * DN + d) * 5 + 1];
  const float ot2 = odd_tensor[(a * DN + d) * 5 + 2];
  const float ot3 = odd_tensor[(a * DN + d) * 5 + 3];
  const float ot4 = odd_tensor[(a * DN + d) * 5 + 4];

  const float w0 = W[0 * DN + d];
  const float w1 = W[1 * DN + d];
  const float w2 = W[2 * DN + d];
  const float w3 = W[3 * DN + d];
  const float w4 = W[4 * DN + d];
  const float w5 = W[5 * DN + d];
  const float w6 = W[6 * DN + d];
  const float w7 = W[7 * DN + d];
  const float w8 = W[8 * DN + d];
  const float w9 = W[9 * DN + d];

  float r[34];
  r[0]  = es * w0;
  r[1]  = os * w1;
  r[2]  = ov0 * w2; r[3]  = ov1 * w2; r[4]  = ov2 * w2;
  r[5]  = ev0 * w3; r[6]  = ev1 * w3; r[7]  = ev2 * w3;
  r[8]  = et0 * w4; r[9]  = et1 * w4; r[10] = et2 * w4; r[11] = et3 * w4; r[12] = et4 * w4;
  r[13] = ot0 * w5; r[14] = ot1 * w5; r[15] = ot2 * w5; r[16] = ot3 * w5; r[17] = ot4 * w5;
  r[18] = ov0 * w6; r[19] = ov1 * w6; r[20] = ov2 * w6;
  r[21] = ev0 * w7; r[22] = ev1 * w7; r[23] = ev2 * w7;
  r[24] = et0 * w8; r[25] = et1 * w8; r[26] = et2 * w8; r[27] = et3 * w8; r[28] = et4 * w8;
  r[29] = ot0 * w9; r[30] = ot1 * w9; r[31] = ot2 * w9; r[32] = ot3 * w9; r[33] = ot4 * w9;

#pragma unroll
  for (int k = 0; k < 34; ++k) r[k] = wave_sum(r[k]);

  if (d == 0) {
    float* o = out + (size_t)a * AS2;
    o[0] = atom_coords[a * 3 + 0];
    o[1] = atom_coords[a * 3 + 1];
    o[2] = atom_coords[a * 3 + 2];
    o[3] = -alpha[a] * LOG2Ef;
    o[4] = r[0] + b[0];
    o[5] = r[1] + b[1];
    o[6] = r[2] + b[2]; o[7] = r[3] + b[2]; o[8] = r[4] + b[2];
    o[9] = r[5] + b[3]; o[10] = r[6] + b[3]; o[11] = r[7] + b[3];
    {
      float c0 = r[8] + b[4], c1 = r[9] + b[4], c2 = r[10] + b[4],
            c3 = r[11] + b[4], c4 = r[12] + b[4];
      float zz = c1 * 0.816496580927726f;
      float xx = 0.5f * (c0 * SQ2f - zz);
      float yy = 0.5f * (-c0 * SQ2f - zz);
      float xy = c2 * INV_SQ2f, xz = c3 * INV_SQ2f, yz = c4 * INV_SQ2f;
      o[12] = xx; o[13] = xy; o[14] = xz; o[15] = yy; o[16] = yz; o[17] = zz;
    }
    {
      float c0 = r[13] + b[5], c1 = r[14] + b[5], c2 = r[15] + b[5],
            c3 = r[16] + b[5], c4 = r[17] + b[5];
      float zz = c1 * 0.816496580927726f;
      float xx = 0.5f * (c0 * SQ2f - zz);
      float yy = 0.5f * (-c0 * SQ2f - zz);
      float xy = c2 * INV_SQ2f, xz = c3 * INV_SQ2f, yz = c4 * INV_SQ2f;
      o[18] = xx; o[19] = xy; o[20] = xz; o[21] = yy; o[22] = yz; o[23] = zz;
    }
    o[24] = r[18]; o[25] = r[19]; o[26] = r[20];     // le
    o[27] = r[21]; o[28] = r[22]; o[29] = r[23];     // lo
    {
      float A0 = r[24] * INV_SQ2f, A1 = r[25] * SQ6_INVf;
      float A2 = r[26] * SQ2f, A3 = r[27] * SQ2f, A4 = r[28] * SQ2f;
      o[30] = A0 - A1; o[31] = -A0 - A1; o[32] = 2.0f * A1;
      o[33] = A2; o[34] = A3; o[35] = A4;
    }
    {
      float A0 = r[29] * INV_SQ2f, A1 = r[30] * SQ6_INVf;
      float A2 = r[31] * SQ2f, A3 = r[32] * SQ2f, A4 = r[33] * SQ2f;
      o[36] = A0 - A1; o[37] = -A0 - A1; o[38] = 2.0f * A1;
      o[39] = A2; o[40] = A3; o[41] = A4;
    }
    o[42] = 0.f; o[43] = 0.f;
  }
}

// ---------------- Kernel A2: pack per-atom MFMA coefficient matrix ----------
// Mh layout per atom (256 f16): [khalf][f][8]:
//   khalf 0, slot j = coeff on monomial m=j; khalf 1, slot 0 = coeff on m8.
// Monomials U[m] = [w, g1*dx, g1*dy, g1*dz, g2*xx, g2*yy, g2*xy, g2*xz, g2*yz]
// where g1=w/d, g2=w/d2 (so m1..3 = w*unit, m4.. = w*unit quadratics; zz folded
// into m0 via xx+yy+zz=1).
__global__ __launch_bounds__(256) void pack_m(
    const float* __restrict__ ad, _Float16* __restrict__ Mh,
    float4* __restrict__ atomC)
{
  const int g = blockIdx.x * 256 + threadIdx.x;   // a*16 + f
  const int a = g >> 4, f = g & 15;
  const float* o = ad + (size_t)a * AS2;
  float m[9];
#pragma unroll
  for (int k = 0; k < 9; ++k) m[k] = 0.f;
  switch (f) {
    case 0: m[0] = 1.f; break;
    case 1: m[0] = o[4]; break;
    case 2: m[0] = o[5]; break;
    case 3: m[0]=o[6];  m[1]=o[12]; m[2]=o[13]; m[3]=o[14]; break;
    case 4: m[0]=o[7];  m[1]=o[13]; m[2]=o[15]; m[3]=o[16]; break;
    case 5: m[0]=o[8];  m[1]=o[14]; m[2]=o[16]; m[3]=o[17]; break;
    case 6: m[0]=o[9];  m[1]=o[18]; m[2]=o[19]; m[3]=o[20]; break;
    case 7: m[0]=o[10]; m[1]=o[19]; m[2]=o[21]; m[3]=o[22]; break;
    case 8: m[0]=o[11]; m[1]=o[20]; m[2]=o[22]; m[3]=o[23]; break;
    case 9:  m[0]=o[32]; m[1]=o[24]; m[2]=o[25]; m[3]=o[26];
             m[4]=o[30]-o[32]; m[5]=o[31]-o[32];
             m[6]=o[33]; m[7]=o[34]; m[8]=o[35]; break;
    case 10: m[0]=o[38]; m[1]=o[27]; m[2]=o[28]; m[3]=o[29];
             m[4]=o[36]-o[38]; m[5]=o[37]-o[38];
             m[6]=o[39]; m[7]=o[40]; m[8]=o[41]; break;
    default: break;
  }
  _Float16* dst = Mh + (size_t)a * 256;
#pragma unroll
  for (int k = 0; k < 8; ++k) dst[f * 8 + k] = (_Float16)m[k];
  dst[128 + f * 8 + 0] = (_Float16)m[8];
#pragma unroll
  for (int k = 1; k < 8; ++k) dst[128 + f * 8 + k] = (_Float16)0.f;
  if (f == 0) {
    atomC[a] = make_float4(o[0], o[1], o[2], o[3]);
  }
}

// ---------------- Kernel B: MFMA splat ----------------
// Per wave: 16 queries x 16 fields, K-loop over 64 atoms (2 atoms per MFMA).
// D[f][q] = sum_k M[f][k] * U[k][q];  A-frag = M (f=lane&15, k=(lane>>4)*8+j),
// B-frag = U (q=lane&15, same k-slots), C/D: col=lane&15 (q), row=(lane>>4)*4+r (f).
__global__ __launch_bounds__(256, 4) void mfma_splat(
    const float* __restrict__ qcoord, const _Float16* __restrict__ Mh,
    const float4* __restrict__ atomC, float* __restrict__ P)
{
  __shared__ __align__(16) _Float16 smM[CHUNK * 256];
  __shared__ float4 smC[CHUNK];
  const int tid = threadIdx.x;
  const int abase = blockIdx.y * CHUNK;

  {
    const float4* src = (const float4*)(Mh + (size_t)abase * 256);
    float4* dst = (float4*)smM;
#pragma unroll
    for (int t = 0; t < (CHUNK * 256) / (8 * 256); ++t)
      dst[tid + t * 256] = src[tid + t * 256];
  }
  if (tid < CHUNK) smC[tid] = atomC[abase + tid];

  const int lane = tid & 63;
  const int wid = tid >> 6;
  const int fq = lane & 15;                  // f-row for A, q-col for B
  const int q = blockIdx.x * 64 + wid * 16 + fq;
  const float qx = qcoord[q * 3 + 0];
  const float qy = qcoord[q * 3 + 1];
  const float qz = qcoord[q * 3 + 2];
  const int asub = lane >> 5;                // which atom of the pair
  const int mh = (lane >> 4) & 1;            // which k-half (m0..7 / m8..15)
  const _Float16* aptr = smM + (size_t)(asub * 256 + mh * 128 + fq * 8);

  __syncthreads();

  f32x4 acc = {0.f, 0.f, 0.f, 0.f};
  for (int p = 0; p < CHUNK / 2; ++p) {
    const half8 afrag = *(const half8*)(aptr + (size_t)p * 512);
    const float4 ca = smC[p * 2 + asub];
    const float dx = qx - ca.x, dy = qy - ca.y, dz = qz - ca.z;
    const float d2 = fmaf(dx, dx, fmaf(dy, dy, dz * dz));
    const float w = __builtin_amdgcn_exp2f(ca.w * d2);   // ca.w = -alpha*log2e
    const float inv = __builtin_amdgcn_rsqf(d2);
    const float inv2 = inv * inv;
    const float g1 = w * inv, g2 = w * inv2;
    const float m1 = g1 * dx, m2 = g1 * dy, m3 = g1 * dz;
    const float m4 = g2 * (dx * dx), m5 = g2 * (dy * dy);
    const float m6 = g2 * (dx * dy), m7 = g2 * (dx * dz);
    const float m8 = g2 * (dy * dz);

    half8 bfrag;
    bfrag[0] = (_Float16)(mh ? m8 : w);
    bfrag[1] = (_Float16)(mh ? 0.f : m1);
    bfrag[2] = (_Float16)(mh ? 0.f : m2);
    bfrag[3] = (_Float16)(mh ? 0.f : m3);
    bfrag[4] = (_Float16)(mh ? 0.f : m4);
    bfrag[5] = (_Float16)(mh ? 0.f : m5);
    bfrag[6] = (_Float16)(mh ? 0.f : m6);
    bfrag[7] = (_Float16)(mh ? 0.f : m7);

    acc = __builtin_amdgcn_mfma_f32_16x16x32_f16(afrag, bfrag, acc, 0, 0, 0);
  }

  float* Pb = P + (size_t)blockIdx.y * 16 * QN + blockIdx.x * 64 + wid * 16 + fq;
#pragma unroll
  for (int r = 0; r < 4; ++r) {
    const int f = (lane >> 4) * 4 + r;
    if (f < 11) Pb[(size_t)f * QN] = acc[r];
  }
}

// ---------------- Kernel C: reduce split partials + finalize ----------------
__global__ __launch_bounds__(256) void reduce_combine(
    const float* __restrict__ P, const float* __restrict__ b,
    float* __restrict__ out)
{
  const int q = blockIdx.x * 256 + threadIdx.x;
  float acc[11];
#pragma unroll
  for (int f = 0; f < 11; ++f) acc[f] = 0.f;
  for (int s = 0; s < NSPLIT; ++s) {
    const float* Ps = P + (size_t)s * 16 * QN + q;
#pragma unroll
    for (int f = 0; f < 11; ++f) acc[f] += Ps[(size_t)f * QN];
  }

  const float b_ea = b[6] + b[8];
  const float b_oa = b[7] + b[9];

  const float Sw = fmaxf(acc[0], 1e-8f);
  const float inv = 1.0f / Sw;
  const float snw = acc[0] * inv;
  const float scal = acc[1] * inv;
  const float pse  = acc[2] * inv;
  const float vx = acc[3] * inv;
  const float vy = acc[4] * inv;
  const float vz = acc[5] * inv;
  const float bx = acc[6] * inv;
  const float by = acc[7] * inv;
  const float bz = acc[8] * inv;
  const float ea = fmaf(b_ea, snw, acc[9] * inv);
  const float oa = fmaf(b_oa, snw, acc[10] * inv);

  const float evenc = scal + ea;
  const float oddc  = pse + oa;
  const float vn = sqrtf(fmaf(vx, vx, fmaf(vy, vy, vz * vz)));
  const float bn = sqrtf(fmaf(bx, bx, fmaf(by, by, bz * bz)));
  const float total = evenc + oddc + 0.1f * vn + 0.05f * bn;

  out[q] = total;
  out[QN + q] = evenc;
  out[2 * QN + q] = oddc;
  float* mv = out + 3 * QN + (size_t)q * 16;
  mv[0] = scal;
  mv[1] = vx; mv[2] = vy; mv[3] = vz;
  mv[4] = 0.f;
  mv[5] = bz; mv[6] = -by; mv[7] = bx;
  mv[8] = 0.f; mv[9] = 0.f; mv[10] = 0.f;
  mv[11] = pse;
  mv[12] = 0.f; mv[13] = 0.f; mv[14] = 0.f; mv[15] = 0.f;
}

extern "C" void kernel_launch(void* const* d_in, const int* in_sizes, int n_in,
                              void* d_out, int out_size, void* d_ws, size_t ws_size,
                              hipStream_t stream) {
  const float* query_coords = (const float*)d_in[0];
  const float* atom_coords  = (const float*)d_in[1];
  const float* alpha        = (const float*)d_in[2];
  const float* even_scalar  = (const float*)d_in[3];
  const float* odd_scalar   = (const float*)d_in[4];
  const float* odd_vector   = (const float*)d_in[5];
  const float* even_vector  = (const float*)d_in[6];
  const float* even_tensor  = (const float*)d_in[7];
  const float* odd_tensor   = (const float*)d_in[8];
  const float* W            = (const float*)d_in[9];
  const float* b            = (const float*)d_in[10];
  float* out = (float*)d_out;

  const size_t adBytes = (size_t)AN * AS2 * sizeof(float);            // 360448
  char* ws = (char*)d_ws;
  float*     ad     = (float*)ws;
  _Float16*  Mh     = (_Float16*)(ws + adBytes);                      // 1 MB
  float4*    atomCp = (float4*)(ws + adBytes + (size_t)AN * 256 * 2); // 32 KB
  float*     P      = (float*)(ws + adBytes + (size_t)AN * 256 * 2
                               + (size_t)AN * sizeof(float4));        // 16 MB

  precompute_atoms<<<AN / 4, 256, 0, stream>>>(
      atom_coords, alpha, even_scalar, odd_scalar, odd_vector, even_vector,
      even_tensor, odd_tensor, W, b, ad);
  pack_m<<<(AN * 16) / 256, 256, 0, stream>>>(ad, Mh, atomCp);
  mfma_splat<<<dim3(QN / 64, NSPLIT), 256, 0, stream>>>(
      query_coords, Mh, atomCp, P);
  reduce_combine<<<QN / 256, 256, 0, stream>>>(P, b, out);
}

// Round 7
// 45.052 us; speedup vs baseline: 1.7958x; 1.5931x over previous
//
#include <hip/hip_runtime.h>
#include <math.h>

#define QN 8192
#define AN 2048
#define DN 64
#define AS2 44          // floats per atom record (precompute output)
#define NSPLIT 32
#define CHUNK 64        // atoms per block in mfma_splat
#define AH 136          // halfs per atom in packed M (17 float4, bank-spread pad)

#define SQ2f      1.4142135623730951f
#define INV_SQ2f  0.7071067811865476f
#define SQ6_INVf  0.4082482904638631f
#define LOG2Ef    1.4426950408889634f

typedef __attribute__((ext_vector_type(8))) _Float16 half8;
typedef __attribute__((ext_vector_type(4))) float f32x4;

__device__ __forceinline__ float wave_sum(float v) {
#pragma unroll
  for (int off = 32; off > 0; off >>= 1) v += __shfl_xor(v, off, 64);
  return v;
}

__device__ __forceinline__ unsigned pkh(float a, float b) {
  auto h = __builtin_amdgcn_cvt_pkrtz(a, b);   // __fp16 ext_vector(2)
  return __builtin_bit_cast(unsigned, h);
}

// ---------------- Kernel A: per-atom precompute (unchanged, proven) ---------
__global__ __launch_bounds__(256) void precompute_atoms(
    const float* __restrict__ atom_coords, const float* __restrict__ alpha,
    const float* __restrict__ even_scalar, const float* __restrict__ odd_scalar,
    const float* __restrict__ odd_vector, const float* __restrict__ even_vector,
    const float* __restrict__ even_tensor, const float* __restrict__ odd_tensor,
    const float* __restrict__ W, const float* __restrict__ b,
    float* __restrict__ out)
{
  const int a = blockIdx.x * 4 + (threadIdx.x >> 6);
  const int d = threadIdx.x & 63;

  const float es  = even_scalar[a * DN + d];
  const float os  = odd_scalar[a * DN + d];
  const float ov0 = odd_vector[(a * DN + d) * 3 + 0];
  const float ov1 = odd_vector[(a * DN + d) * 3 + 1];
  const float ov2 = odd_vector[(a * DN + d) * 3 + 2];
  const float ev0 = even_vector[(a * DN + d) * 3 + 0];
  const float ev1 = even_vector[(a * DN + d) * 3 + 1];
  const float ev2 = even_vector[(a * DN + d) * 3 + 2];
  const float et0 = even_tensor[(a * DN + d) * 5 + 0];
  const float et1 = even_tensor[(a * DN + d) * 5 + 1];
  const float et2 = even_tensor[(a * DN + d) * 5 + 2];
  const float et3 = even_tensor[(a * DN + d) * 5 + 3];
  const float et4 = even_tensor[(a * DN + d) * 5 + 4];
  const float ot0 = odd_tensor[(a * DN + d) * 5 + 0];
  const float ot1 = odd_tensor[(a * DN + d) * 5 + 1];
  const float ot2 = odd_tensor[(a * DN + d) * 5 + 2];
  const float ot3 = odd_tensor[(a * DN + d) * 5 + 3];
  const float ot4 = odd_tensor[(a * DN + d) * 5 + 4];

  const float w0 = W[0 * DN + d];
  const float w1 = W[1 * DN + d];
  const float w2 = W[2 * DN + d];
  const float w3 = W[3 * DN + d];
  const float w4 = W[4 * DN + d];
  const float w5 = W[5 * DN + d];
  const float w6 = W[6 * DN + d];
  const float w7 = W[7 * DN + d];
  const float w8 = W[8 * DN + d];
  const float w9 = W[9 * DN + d];

  float r[34];
  r[0]  = es * w0;
  r[1]  = os * w1;
  r[2]  = ov0 * w2; r[3]  = ov1 * w2; r[4]  = ov2 * w2;
  r[5]  = ev0 * w3; r[6]  = ev1 * w3; r[7]  = ev2 * w3;
  r[8]  = et0 * w4; r[9]  = et1 * w4; r[10] = et2 * w4; r[11] = et3 * w4; r[12] = et4 * w4;
  r[13] = ot0 * w5; r[14] = ot1 * w5; r[15] = ot2 * w5; r[16] = ot3 * w5; r[17] = ot4 * w5;
  r[18] = ov0 * w6; r[19] = ov1 * w6; r[20] = ov2 * w6;
  r[21] = ev0 * w7; r[22] = ev1 * w7; r[23] = ev2 * w7;
  r[24] = et0 * w8; r[25] = et1 * w8; r[26] = et2 * w8; r[27] = et3 * w8; r[28] = et4 * w8;
  r[29] = ot0 * w9; r[30] = ot1 * w9; r[31] = ot2 * w9; r[32] = ot3 * w9; r[33] = ot4 * w9;

#pragma unroll
  for (int k = 0; k < 34; ++k) r[k] = wave_sum(r[k]);

  if (d == 0) {
    float* o = out + (size_t)a * AS2;
    o[0] = atom_coords[a * 3 + 0];
    o[1] = atom_coords[a * 3 + 1];
    o[2] = atom_coords[a * 3 + 2];
    o[3] = -alpha[a] * LOG2Ef;
    o[4] = r[0] + b[0];
    o[5] = r[1] + b[1];
    o[6] = r[2] + b[2]; o[7] = r[3] + b[2]; o[8] = r[4] + b[2];
    o[9] = r[5] + b[3]; o[10] = r[6] + b[3]; o[11] = r[7] + b[3];
    {
      float c0 = r[8] + b[4], c1 = r[9] + b[4], c2 = r[10] + b[4],
            c3 = r[11] + b[4], c4 = r[12] + b[4];
      float zz = c1 * 0.816496580927726f;
      float xx = 0.5f * (c0 * SQ2f - zz);
      float yy = 0.5f * (-c0 * SQ2f - zz);
      float xy = c2 * INV_SQ2f, xz = c3 * INV_SQ2f, yz = c4 * INV_SQ2f;
      o[12] = xx; o[13] = xy; o[14] = xz; o[15] = yy; o[16] = yz; o[17] = zz;
    }
    {
      float c0 = r[13] + b[5], c1 = r[14] + b[5], c2 = r[15] + b[5],
            c3 = r[16] + b[5], c4 = r[17] + b[5];
      float zz = c1 * 0.816496580927726f;
      float xx = 0.5f * (c0 * SQ2f - zz);
      float yy = 0.5f * (-c0 * SQ2f - zz);
      float xy = c2 * INV_SQ2f, xz = c3 * INV_SQ2f, yz = c4 * INV_SQ2f;
      o[18] = xx; o[19] = xy; o[20] = xz; o[21] = yy; o[22] = yz; o[23] = zz;
    }
    o[24] = r[18]; o[25] = r[19]; o[26] = r[20];     // le
    o[27] = r[21]; o[28] = r[22]; o[29] = r[23];     // lo
    {
      float A0 = r[24] * INV_SQ2f, A1 = r[25] * SQ6_INVf;
      float A2 = r[26] * SQ2f, A3 = r[27] * SQ2f, A4 = r[28] * SQ2f;
      o[30] = A0 - A1; o[31] = -A0 - A1; o[32] = 2.0f * A1;
      o[33] = A2; o[34] = A3; o[35] = A4;
    }
    {
      float A0 = r[29] * INV_SQ2f, A1 = r[30] * SQ6_INVf;
      float A2 = r[31] * SQ2f, A3 = r[32] * SQ2f, A4 = r[33] * SQ2f;
      o[36] = A0 - A1; o[37] = -A0 - A1; o[38] = 2.0f * A1;
      o[39] = A2; o[40] = A3; o[41] = A4;
    }
    o[42] = 0.f; o[43] = 0.f;
  }
}

// ---------------- Kernel A2: pack A-matrices (f16), one thread per (a,row) --
// Per-atom block (AH=136 halfs):
//   0..95   : A1 rows 0..11 (row r at r*8), slots [w, m1, m2, m3, 0,0,0,0]
//   96..103 : A2 row for field 9, slots [xx, yy, xy, xz, yz, 0,0,0]
//   104..111: A2 row for field 10
//   112..119: A2 zero row (for all other fq)
//   120..135: pad
__global__ __launch_bounds__(256) void pack_m(
    const float* __restrict__ ad, _Float16* __restrict__ Mh,
    float4* __restrict__ atomC)
{
  const int idx = blockIdx.x * 256 + threadIdx.x;   // a*16 + r
  const int a = idx >> 4, r = idx & 15;
  const float* o = ad + (size_t)a * AS2;

  float m[8];
#pragma unroll
  for (int k = 0; k < 8; ++k) m[k] = 0.f;
  int off = 0;   // half-offset within atom block

  switch (r) {
    case 0:  off = 0;   m[0] = 1.f; break;
    case 1:  off = 8;   m[0] = o[4]; break;
    case 2:  off = 16;  m[0] = o[5]; break;
    case 3:  off = 24;  m[0]=o[6];  m[1]=o[12]; m[2]=o[13]; m[3]=o[14]; break;
    case 4:  off = 32;  m[0]=o[7];  m[1]=o[13]; m[2]=o[15]; m[3]=o[16]; break;
    case 5:  off = 40;  m[0]=o[8];  m[1]=o[14]; m[2]=o[16]; m[3]=o[17]; break;
    case 6:  off = 48;  m[0]=o[9];  m[1]=o[18]; m[2]=o[19]; m[3]=o[20]; break;
    case 7:  off = 56;  m[0]=o[10]; m[1]=o[19]; m[2]=o[21]; m[3]=o[22]; break;
    case 8:  off = 64;  m[0]=o[11]; m[1]=o[20]; m[2]=o[22]; m[3]=o[23]; break;
    case 9:  off = 72;  m[0]=o[32]; m[1]=o[24]; m[2]=o[25]; m[3]=o[26]; break;
    case 10: off = 80;  m[0]=o[38]; m[1]=o[27]; m[2]=o[28]; m[3]=o[29]; break;
    case 11: off = 88;  break;                               // A1 zero row
    case 12: off = 96;  m[0]=o[30]-o[32]; m[1]=o[31]-o[32];  // A2 field 9
             m[2]=o[33]; m[3]=o[34]; m[4]=o[35]; break;
    case 13: off = 104; m[0]=o[36]-o[38]; m[1]=o[37]-o[38];  // A2 field 10
             m[2]=o[39]; m[3]=o[40]; m[4]=o[41]; break;
    case 14: off = 112; break;                               // A2 zero row
    case 15: off = 120; break;                               // pad (zeros)
  }

  union { unsigned u[4]; half8 h; } row;
  row.u[0] = pkh(m[0], m[1]);
  row.u[1] = pkh(m[2], m[3]);
  row.u[2] = pkh(m[4], m[5]);
  row.u[3] = pkh(m[6], m[7]);
  *(half8*)(Mh + (size_t)a * AH + off) = row.h;

  if (r == 0) atomC[a] = make_float4(o[0], o[1], o[2], o[3]);
}

// ---------------- Kernel B: MFMA splat, 4 atoms / 2 MFMAs per iter ----------
// Per wave: 16 queries x 16 fields. K=32 = 4 atoms x 8 slots; lane group
// g=(lane>>4) owns atom g of the group. Two MFMAs share one accumulator:
//   pass1 slots [w, g1dx, g1dy, g1dz], pass2 slots [g2xx, g2yy, g2xy, g2xz, g2yz].
__global__ __launch_bounds__(256, 4) void mfma_splat(
    const float* __restrict__ qcoord, const _Float16* __restrict__ Mh,
    const float4* __restrict__ atomC, float* __restrict__ P)
{
  __shared__ __align__(16) _Float16 smM[CHUNK * AH];
  __shared__ float4 smC[CHUNK];
  const int tid = threadIdx.x;
  const int abase = blockIdx.y * CHUNK;

  // stage packed A-matrices (CHUNK*17 float4 = 1088) + coords
  {
    const float4* src = (const float4*)(Mh + (size_t)abase * AH);
    float4* dst = (float4*)smM;
#pragma unroll
    for (int t = 0; t < 4; ++t) dst[tid + t * 256] = src[tid + t * 256];
    if (tid < 64) dst[1024 + tid] = src[1024 + tid];
  }
  if (tid < CHUNK) smC[tid] = atomC[abase + tid];

  const int lane = tid & 63;
  const int wid = tid >> 6;
  const int fq = lane & 15;                  // f-row for A, q-col for B
  const int g = (lane >> 4) & 3;             // atom within group of 4
  const int q = blockIdx.x * 64 + wid * 16 + fq;
  const float qx = qcoord[q * 3 + 0];
  const float qy = qcoord[q * 3 + 1];
  const float qz = qcoord[q * 3 + 2];

  const int a1off = (fq < 11 ? fq : 11) * 8;
  const int a2off = 96 + (fq == 9 ? 0 : (fq == 10 ? 8 : 16));
  const _Float16* p1 = smM + g * AH + a1off;
  const _Float16* p2 = smM + g * AH + a2off;

  __syncthreads();

  f32x4 acc = {0.f, 0.f, 0.f, 0.f};
#pragma unroll 2
  for (int it = 0; it < CHUNK / 4; ++it) {
    const half8 a1 = *(const half8*)(p1 + it * (4 * AH));
    const half8 a2 = *(const half8*)(p2 + it * (4 * AH));
    const float4 ca = smC[it * 4 + g];

    const float dx = qx - ca.x, dy = qy - ca.y, dz = qz - ca.z;
    const float d2 = fmaf(dx, dx, fmaf(dy, dy, dz * dz));
    const float w = __builtin_amdgcn_exp2f(ca.w * d2);   // ca.w = -alpha*log2e
    const float inv = __builtin_amdgcn_rsqf(d2);
    const float g1 = w * inv;
    const float g2 = g1 * inv;
    const float m1 = g1 * dx, m2 = g1 * dy, m3 = g1 * dz;
    const float t = g2 * dx, u = g2 * dy;
    const float m4 = t * dx, m6 = t * dy, m7 = t * dz;
    const float m5 = u * dy, m8 = u * dz;

    union { unsigned uu[4]; half8 h; } b1, b2;
    b1.uu[0] = pkh(w, m1);  b1.uu[1] = pkh(m2, m3);
    b1.uu[2] = 0u;          b1.uu[3] = 0u;
    b2.uu[0] = pkh(m4, m5); b2.uu[1] = pkh(m6, m7);
    b2.uu[2] = pkh(m8, 0.f); b2.uu[3] = 0u;

    acc = __builtin_amdgcn_mfma_f32_16x16x32_f16(a1, b1.h, acc, 0, 0, 0);
    acc = __builtin_amdgcn_mfma_f32_16x16x32_f16(a2, b2.h, acc, 0, 0, 0);
  }

  float* Pb = P + (size_t)blockIdx.y * 16 * QN + q;
#pragma unroll
  for (int r = 0; r < 4; ++r) {
    const int f = (lane >> 4) * 4 + r;
    if (f < 11) Pb[(size_t)f * QN] = acc[r];
  }
}

// ---------------- Kernel C: reduce split partials + finalize (proven) -------
__global__ __launch_bounds__(256) void reduce_combine(
    const float* __restrict__ P, const float* __restrict__ b,
    float* __restrict__ out)
{
  const int q = blockIdx.x * 256 + threadIdx.x;
  float acc[11];
#pragma unroll
  for (int f = 0; f < 11; ++f) acc[f] = 0.f;
  for (int s = 0; s < NSPLIT; ++s) {
    const float* Ps = P + (size_t)s * 16 * QN + q;
#pragma unroll
    for (int f = 0; f < 11; ++f) acc[f] += Ps[(size_t)f * QN];
  }

  const float b_ea = b[6] + b[8];
  const float b_oa = b[7] + b[9];

  const float Sw = fmaxf(acc[0], 1e-8f);
  const float inv = 1.0f / Sw;
  const float snw = acc[0] * inv;
  const float scal = acc[1] * inv;
  const float pse  = acc[2] * inv;
  const float vx = acc[3] * inv;
  const float vy = acc[4] * inv;
  const float vz = acc[5] * inv;
  const float bx = acc[6] * inv;
  const float by = acc[7] * inv;
  const float bz = acc[8] * inv;
  const float ea = fmaf(b_ea, snw, acc[9] * inv);
  const float oa = fmaf(b_oa, snw, acc[10] * inv);

  const float evenc = scal + ea;
  const float oddc  = pse + oa;
  const float vn = sqrtf(fmaf(vx, vx, fmaf(vy, vy, vz * vz)));
  const float bn = sqrtf(fmaf(bx, bx, fmaf(by, by, bz * bz)));
  const float total = evenc + oddc + 0.1f * vn + 0.05f * bn;

  out[q] = total;
  out[QN + q] = evenc;
  out[2 * QN + q] = oddc;
  float* mv = out + 3 * QN + (size_t)q * 16;
  mv[0] = scal;
  mv[1] = vx; mv[2] = vy; mv[3] = vz;
  mv[4] = 0.f;
  mv[5] = bz; mv[6] = -by; mv[7] = bx;
  mv[8] = 0.f; mv[9] = 0.f; mv[10] = 0.f;
  mv[11] = pse;
  mv[12] = 0.f; mv[13] = 0.f; mv[14] = 0.f; mv[15] = 0.f;
}

extern "C" void kernel_launch(void* const* d_in, const int* in_sizes, int n_in,
                              void* d_out, int out_size, void* d_ws, size_t ws_size,
                              hipStream_t stream) {
  const float* query_coords = (const float*)d_in[0];
  const float* atom_coords  = (const float*)d_in[1];
  const float* alpha        = (const float*)d_in[2];
  const float* even_scalar  = (const float*)d_in[3];
  const float* odd_scalar   = (const float*)d_in[4];
  const float* odd_vector   = (const float*)d_in[5];
  const float* even_vector  = (const float*)d_in[6];
  const float* even_tensor  = (const float*)d_in[7];
  const float* odd_tensor   = (const float*)d_in[8];
  const float* W            = (const float*)d_in[9];
  const float* b            = (const float*)d_in[10];
  float* out = (float*)d_out;

  const size_t adBytes = (size_t)AN * AS2 * sizeof(float);          // 360448
  const size_t mhBytes = (size_t)AN * AH * sizeof(_Float16);        // 557056
  char* ws = (char*)d_ws;
  float*     ad     = (float*)ws;
  _Float16*  Mh     = (_Float16*)(ws + adBytes);
  float4*    atomCp = (float4*)(ws + adBytes + mhBytes);
  float*     P      = (float*)(ws + adBytes + mhBytes
                               + (size_t)AN * sizeof(float4));

  precompute_atoms<<<AN / 4, 256, 0, stream>>>(
      atom_coords, alpha, even_scalar, odd_scalar, odd_vector, even_vector,
      even_tensor, odd_tensor, W, b, ad);
  pack_m<<<(AN * 16) / 256, 256, 0, stream>>>(ad, Mh, atomCp);
  mfma_splat<<<dim3(QN / 64, NSPLIT), 256, 0, stream>>>(
      query_coords, Mh, atomCp, P);
  reduce_combine<<<QN / 256, 256, 0, stream>>>(P, b, out);
}

// Round 8
// 42.666 us; speedup vs baseline: 1.8963x; 1.0559x over previous
//
#include <hip/hip_runtime.h>
#include <math.h>

#define QN 8192
#define AN 2048
#define DN 64
#define AS2 44          // floats per atom record (precompute output)
#define NSPLIT 32
#define CHUNK 64        // atoms per block in mfma_splat
#define AH 136          // halfs per atom in packed M (17 float4, bank-spread pad)

#define SQ2f      1.4142135623730951f
#define INV_SQ2f  0.7071067811865476f
#define SQ6_INVf  0.4082482904638631f
#define LOG2Ef    1.4426950408889634f

typedef __attribute__((ext_vector_type(8))) _Float16 half8;
typedef __attribute__((ext_vector_type(4))) float f32x4;

__device__ __forceinline__ float wave_sum(float v) {
#pragma unroll
  for (int off = 32; off > 0; off >>= 1) v += __shfl_xor(v, off, 64);
  return v;
}

__device__ __forceinline__ unsigned pkh(float a, float b) {
  auto h = __builtin_amdgcn_cvt_pkrtz(a, b);   // __fp16 ext_vector(2)
  return __builtin_bit_cast(unsigned, h);
}

// ---------------- Kernel A: per-atom precompute (unchanged, proven) ---------
__global__ __launch_bounds__(256) void precompute_atoms(
    const float* __restrict__ atom_coords, const float* __restrict__ alpha,
    const float* __restrict__ even_scalar, const float* __restrict__ odd_scalar,
    const float* __restrict__ odd_vector, const float* __restrict__ even_vector,
    const float* __restrict__ even_tensor, const float* __restrict__ odd_tensor,
    const float* __restrict__ W, const float* __restrict__ b,
    float* __restrict__ out)
{
  const int a = blockIdx.x * 4 + (threadIdx.x >> 6);
  const int d = threadIdx.x & 63;

  const float es  = even_scalar[a * DN + d];
  const float os  = odd_scalar[a * DN + d];
  const float ov0 = odd_vector[(a * DN + d) * 3 + 0];
  const float ov1 = odd_vector[(a * DN + d) * 3 + 1];
  const float ov2 = odd_vector[(a * DN + d) * 3 + 2];
  const float ev0 = even_vector[(a * DN + d) * 3 + 0];
  const float ev1 = even_vector[(a * DN + d) * 3 + 1];
  const float ev2 = even_vector[(a * DN + d) * 3 + 2];
  const float et0 = even_tensor[(a * DN + d) * 5 + 0];
  const float et1 = even_tensor[(a * DN + d) * 5 + 1];
  const float et2 = even_tensor[(a * DN + d) * 5 + 2];
  const float et3 = even_tensor[(a * DN + d) * 5 + 3];
  const float et4 = even_tensor[(a * DN + d) * 5 + 4];
  const float ot0 = odd_tensor[(a * DN + d) * 5 + 0];
  const float ot1 = odd_tensor[(a * DN + d) * 5 + 1];
  const float ot2 = odd_tensor[(a * DN + d) * 5 + 2];
  const float ot3 = odd_tensor[(a * DN + d) * 5 + 3];
  const float ot4 = odd_tensor[(a * DN + d) * 5 + 4];

  const float w0 = W[0 * DN + d];
  const float w1 = W[1 * DN + d];
  const float w2 = W[2 * DN + d];
  const float w3 = W[3 * DN + d];
  const float w4 = W[4 * DN + d];
  const float w5 = W[5 * DN + d];
  const float w6 = W[6 * DN + d];
  const float w7 = W[7 * DN + d];
  const float w8 = W[8 * DN + d];
  const float w9 = W[9 * DN + d];

  float r[34];
  r[0]  = es * w0;
  r[1]  = os * w1;
  r[2]  = ov0 * w2; r[3]  = ov1 * w2; r[4]  = ov2 * w2;
  r[5]  = ev0 * w3; r[6]  = ev1 * w3; r[7]  = ev2 * w3;
  r[8]  = et0 * w4; r[9]  = et1 * w4; r[10] = et2 * w4; r[11] = et3 * w4; r[12] = et4 * w4;
  r[13] = ot0 * w5; r[14] = ot1 * w5; r[15] = ot2 * w5; r[16] = ot3 * w5; r[17] = ot4 * w5;
  r[18] = ov0 * w6; r[19] = ov1 * w6; r[20] = ov2 * w6;
  r[21] = ev0 * w7; r[22] = ev1 * w7; r[23] = ev2 * w7;
  r[24] = et0 * w8; r[25] = et1 * w8; r[26] = et2 * w8; r[27] = et3 * w8; r[28] = et4 * w8;
  r[29] = ot0 * w9; r[30] = ot1 * w9; r[31] = ot2 * w9; r[32] = ot3 * w9; r[33] = ot4 * w9;

#pragma unroll
  for (int k = 0; k < 34; ++k) r[k] = wave_sum(r[k]);

  if (d == 0) {
    float* o = out + (size_t)a * AS2;
    o[0] = atom_coords[a * 3 + 0];
    o[1] = atom_coords[a * 3 + 1];
    o[2] = atom_coords[a * 3 + 2];
    o[3] = -alpha[a] * LOG2Ef;
    o[4] = r[0] + b[0];
    o[5] = r[1] + b[1];
    o[6] = r[2] + b[2]; o[7] = r[3] + b[2]; o[8] = r[4] + b[2];
    o[9] = r[5] + b[3]; o[10] = r[6] + b[3]; o[11] = r[7] + b[3];
    {
      float c0 = r[8] + b[4], c1 = r[9] + b[4], c2 = r[10] + b[4],
            c3 = r[11] + b[4], c4 = r[12] + b[4];
      float zz = c1 * 0.816496580927726f;
      float xx = 0.5f * (c0 * SQ2f - zz);
      float yy = 0.5f * (-c0 * SQ2f - zz);
      float xy = c2 * INV_SQ2f, xz = c3 * INV_SQ2f, yz = c4 * INV_SQ2f;
      o[12] = xx; o[13] = xy; o[14] = xz; o[15] = yy; o[16] = yz; o[17] = zz;
    }
    {
      float c0 = r[13] + b[5], c1 = r[14] + b[5], c2 = r[15] + b[5],
            c3 = r[16] + b[5], c4 = r[17] + b[5];
      float zz = c1 * 0.816496580927726f;
      float xx = 0.5f * (c0 * SQ2f - zz);
      float yy = 0.5f * (-c0 * SQ2f - zz);
      float xy = c2 * INV_SQ2f, xz = c3 * INV_SQ2f, yz = c4 * INV_SQ2f;
      o[18] = xx; o[19] = xy; o[20] = xz; o[21] = yy; o[22] = yz; o[23] = zz;
    }
    o[24] = r[18]; o[25] = r[19]; o[26] = r[20];     // le
    o[27] = r[21]; o[28] = r[22]; o[29] = r[23];     // lo
    {
      float A0 = r[24] * INV_SQ2f, A1 = r[25] * SQ6_INVf;
      float A2 = r[26] * SQ2f, A3 = r[27] * SQ2f, A4 = r[28] * SQ2f;
      o[30] = A0 - A1; o[31] = -A0 - A1; o[32] = 2.0f * A1;
      o[33] = A2; o[34] = A3; o[35] = A4;
    }
    {
      float A0 = r[29] * INV_SQ2f, A1 = r[30] * SQ6_INVf;
      float A2 = r[31] * SQ2f, A3 = r[32] * SQ2f, A4 = r[33] * SQ2f;
      o[36] = A0 - A1; o[37] = -A0 - A1; o[38] = 2.0f * A1;
      o[39] = A2; o[40] = A3; o[41] = A4;
    }
    o[42] = 0.f; o[43] = 0.f;
  }
}

// ---------------- Kernel A2: pack A-matrices (f16), one thread per (a,row) --
// Per-atom block (AH=136 halfs):
//   0..95   : A1 rows 0..11 (row r at r*8), slots [w, m1, m2, m3, 0,0,0,0]
//   96..103 : A2 row for field 9, slots [xx, yy, xy, xz, yz, 0,0,0]
//   104..111: A2 row for field 10
//   112..119: A2 zero row (for all other fq)
//   120..135: pad
__global__ __launch_bounds__(256) void pack_m(
    const float* __restrict__ ad, _Float16* __restrict__ Mh,
    float4* __restrict__ atomC)
{
  const int idx = blockIdx.x * 256 + threadIdx.x;   // a*16 + r
  const int a = idx >> 4, r = idx & 15;
  const float* o = ad + (size_t)a * AS2;

  float m[8];
#pragma unroll
  for (int k = 0; k < 8; ++k) m[k] = 0.f;
  int off = 0;   // half-offset within atom block

  switch (r) {
    case 0:  off = 0;   m[0] = 1.f; break;
    case 1:  off = 8;   m[0] = o[4]; break;
    case 2:  off = 16;  m[0] = o[5]; break;
    case 3:  off = 24;  m[0]=o[6];  m[1]=o[12]; m[2]=o[13]; m[3]=o[14]; break;
    case 4:  off = 32;  m[0]=o[7];  m[1]=o[13]; m[2]=o[15]; m[3]=o[16]; break;
    case 5:  off = 40;  m[0]=o[8];  m[1]=o[14]; m[2]=o[16]; m[3]=o[17]; break;
    case 6:  off = 48;  m[0]=o[9];  m[1]=o[18]; m[2]=o[19]; m[3]=o[20]; break;
    case 7:  off = 56;  m[0]=o[10]; m[1]=o[19]; m[2]=o[21]; m[3]=o[22]; break;
    case 8:  off = 64;  m[0]=o[11]; m[1]=o[20]; m[2]=o[22]; m[3]=o[23]; break;
    case 9:  off = 72;  m[0]=o[32]; m[1]=o[24]; m[2]=o[25]; m[3]=o[26]; break;
    case 10: off = 80;  m[0]=o[38]; m[1]=o[27]; m[2]=o[28]; m[3]=o[29]; break;
    case 11: off = 88;  break;                               // A1 zero row
    case 12: off = 96;  m[0]=o[30]-o[32]; m[1]=o[31]-o[32];  // A2 field 9
             m[2]=o[33]; m[3]=o[34]; m[4]=o[35]; break;
    case 13: off = 104; m[0]=o[36]-o[38]; m[1]=o[37]-o[38];  // A2 field 10
             m[2]=o[39]; m[3]=o[40]; m[4]=o[41]; break;
    case 14: off = 112; break;                               // A2 zero row
    case 15: off = 120; break;                               // pad (zeros)
  }

  union { unsigned u[4]; half8 h; } row;
  row.u[0] = pkh(m[0], m[1]);
  row.u[1] = pkh(m[2], m[3]);
  row.u[2] = pkh(m[4], m[5]);
  row.u[3] = pkh(m[6], m[7]);
  *(half8*)(Mh + (size_t)a * AH + off) = row.h;

  if (r == 0) atomC[a] = make_float4(o[0], o[1], o[2], o[3]);
}

// ---------------- Kernel B: MFMA splat, A-frags reused over 4 q-tiles -------
// Per wave: 64 queries (4 q-tiles of 16) x 16 fields. Per 4-atom group:
// one a1/a2/coords LDS read, then 4x {B-gen + 2 MFMA} with per-tile accs.
__global__ __launch_bounds__(256, 4) void mfma_splat(
    const float* __restrict__ qcoord, const _Float16* __restrict__ Mh,
    const float4* __restrict__ atomC, float* __restrict__ P)
{
  __shared__ __align__(16) _Float16 smM[CHUNK * AH];
  __shared__ float4 smC[CHUNK];
  const int tid = threadIdx.x;
  const int abase = blockIdx.y * CHUNK;

  // stage packed A-matrices (CHUNK*17 float4 = 1088) + coords
  {
    const float4* src = (const float4*)(Mh + (size_t)abase * AH);
    float4* dst = (float4*)smM;
#pragma unroll
    for (int t = 0; t < 4; ++t) dst[tid + t * 256] = src[tid + t * 256];
    if (tid < 64) dst[1024 + tid] = src[1024 + tid];
  }
  if (tid < CHUNK) smC[tid] = atomC[abase + tid];

  const int lane = tid & 63;
  const int wid = tid >> 6;
  const int fq = lane & 15;                  // f-row for A, q-col for B
  const int g = (lane >> 4) & 3;             // atom within group of 4
  const int qb = blockIdx.x * 256 + wid * 64;

  float qx[4], qy[4], qz[4];
#pragma unroll
  for (int jt = 0; jt < 4; ++jt) {
    const int q = qb + jt * 16 + fq;
    qx[jt] = qcoord[q * 3 + 0];
    qy[jt] = qcoord[q * 3 + 1];
    qz[jt] = qcoord[q * 3 + 2];
  }

  const int a1off = (fq < 11 ? fq : 11) * 8;
  const int a2off = 96 + (fq == 9 ? 0 : (fq == 10 ? 8 : 16));
  const _Float16* p1 = smM + g * AH + a1off;
  const _Float16* p2 = smM + g * AH + a2off;

  __syncthreads();

  f32x4 acc[4];
#pragma unroll
  for (int jt = 0; jt < 4; ++jt) acc[jt] = (f32x4){0.f, 0.f, 0.f, 0.f};

  for (int it = 0; it < CHUNK / 4; ++it) {
    const half8 a1 = *(const half8*)(p1 + it * (4 * AH));
    const half8 a2 = *(const half8*)(p2 + it * (4 * AH));
    const float4 ca = smC[it * 4 + g];

#pragma unroll
    for (int jt = 0; jt < 4; ++jt) {
      const float dx = qx[jt] - ca.x, dy = qy[jt] - ca.y, dz = qz[jt] - ca.z;
      const float d2 = fmaf(dx, dx, fmaf(dy, dy, dz * dz));
      const float w = __builtin_amdgcn_exp2f(ca.w * d2); // ca.w = -alpha*log2e
      const float inv = __builtin_amdgcn_rsqf(d2);
      const float g1 = w * inv;
      const float g2 = g1 * inv;
      const float m1 = g1 * dx, m2 = g1 * dy, m3 = g1 * dz;
      const float t = g2 * dx, u = g2 * dy;
      const float m4 = t * dx, m6 = t * dy, m7 = t * dz;
      const float m5 = u * dy, m8 = u * dz;

      union { unsigned uu[4]; half8 h; } b1, b2;
      b1.uu[0] = pkh(w, m1);   b1.uu[1] = pkh(m2, m3);
      b1.uu[2] = 0u;           b1.uu[3] = 0u;
      b2.uu[0] = pkh(m4, m5);  b2.uu[1] = pkh(m6, m7);
      b2.uu[2] = pkh(m8, 0.f); b2.uu[3] = 0u;

      acc[jt] = __builtin_amdgcn_mfma_f32_16x16x32_f16(a1, b1.h, acc[jt], 0, 0, 0);
      acc[jt] = __builtin_amdgcn_mfma_f32_16x16x32_f16(a2, b2.h, acc[jt], 0, 0, 0);
    }
  }

  const int frow = (lane >> 4) * 4;
#pragma unroll
  for (int jt = 0; jt < 4; ++jt) {
    float* Pb = P + (size_t)blockIdx.y * 16 * QN + qb + jt * 16 + fq;
#pragma unroll
    for (int r = 0; r < 4; ++r) {
      const int f = frow + r;
      if (f < 11) Pb[(size_t)f * QN] = acc[jt][r];
    }
  }
}

// ---------------- Kernel C: reduce split partials + finalize (proven) -------
__global__ __launch_bounds__(256) void reduce_combine(
    const float* __restrict__ P, const float* __restrict__ b,
    float* __restrict__ out)
{
  const int q = blockIdx.x * 256 + threadIdx.x;
  float acc[11];
#pragma unroll
  for (int f = 0; f < 11; ++f) acc[f] = 0.f;
  for (int s = 0; s < NSPLIT; ++s) {
    const float* Ps = P + (size_t)s * 16 * QN + q;
#pragma unroll
    for (int f = 0; f < 11; ++f) acc[f] += Ps[(size_t)f * QN];
  }

  const float b_ea = b[6] + b[8];
  const float b_oa = b[7] + b[9];

  const float Sw = fmaxf(acc[0], 1e-8f);
  const float inv = 1.0f / Sw;
  const float snw = acc[0] * inv;
  const float scal = acc[1] * inv;
  const float pse  = acc[2] * inv;
  const float vx = acc[3] * inv;
  const float vy = acc[4] * inv;
  const float vz = acc[5] * inv;
  const float bx = acc[6] * inv;
  const float by = acc[7] * inv;
  const float bz = acc[8] * inv;
  const float ea = fmaf(b_ea, snw, acc[9] * inv);
  const float oa = fmaf(b_oa, snw, acc[10] * inv);

  const float evenc = scal + ea;
  const float oddc  = pse + oa;
  const float vn = sqrtf(fmaf(vx, vx, fmaf(vy, vy, vz * vz)));
  const float bn = sqrtf(fmaf(bx, bx, fmaf(by, by, bz * bz)));
  const float total = evenc + oddc + 0.1f * vn + 0.05f * bn;

  out[q] = total;
  out[QN + q] = evenc;
  out[2 * QN + q] = oddc;
  float* mv = out + 3 * QN + (size_t)q * 16;
  mv[0] = scal;
  mv[1] = vx; mv[2] = vy; mv[3] = vz;
  mv[4] = 0.f;
  mv[5] = bz; mv[6] = -by; mv[7] = bx;
  mv[8] = 0.f; mv[9] = 0.f; mv[10] = 0.f;
  mv[11] = pse;
  mv[12] = 0.f; mv[13] = 0.f; mv[14] = 0.f; mv[15] = 0.f;
}

extern "C" void kernel_launch(void* const* d_in, const int* in_sizes, int n_in,
                              void* d_out, int out_size, void* d_ws, size_t ws_size,
                              hipStream_t stream) {
  const float* query_coords = (const float*)d_in[0];
  const float* atom_coords  = (const float*)d_in[1];
  const float* alpha        = (const float*)d_in[2];
  const float* even_scalar  = (const float*)d_in[3];
  const float* odd_scalar   = (const float*)d_in[4];
  const float* odd_vector   = (const float*)d_in[5];
  const float* even_vector  = (const float*)d_in[6];
  const float* even_tensor  = (const float*)d_in[7];
  const float* odd_tensor   = (const float*)d_in[8];
  const float* W            = (const float*)d_in[9];
  const float* b            = (const float*)d_in[10];
  float* out = (float*)d_out;

  const size_t adBytes = (size_t)AN * AS2 * sizeof(float);          // 360448
  const size_t mhBytes = (size_t)AN * AH * sizeof(_Float16);        // 557056
  char* ws = (char*)d_ws;
  float*     ad     = (float*)ws;
  _Float16*  Mh     = (_Float16*)(ws + adBytes);
  float4*    atomCp = (float4*)(ws + adBytes + mhBytes);
  float*     P      = (float*)(ws + adBytes + mhBytes
                               + (size_t)AN * sizeof(float4));

  precompute_atoms<<<AN / 4, 256, 0, stream>>>(
      atom_coords, alpha, even_scalar, odd_scalar, odd_vector, even_vector,
      even_tensor, odd_tensor, W, b, ad);
  pack_m<<<(AN * 16) / 256, 256, 0, stream>>>(ad, Mh, atomCp);
  mfma_splat<<<dim3(QN / 256, NSPLIT), 256, 0, stream>>>(
      query_coords, Mh, atomCp, P);
  reduce_combine<<<QN / 256, 256, 0, stream>>>(P, b, out);
}

// Round 9
// 36.875 us; speedup vs baseline: 2.1941x; 1.1570x over previous
//
#include <hip/hip_runtime.h>
#include <math.h>

#define QN 8192
#define AN 2048
#define DN 64
#define NSPLIT 32
#define CHUNK 64        // atoms per block in mfma_splat
#define AH 136          // halfs per atom in packed M (17 float4)

#define SQ2f      1.4142135623730951f
#define INV_SQ2f  0.7071067811865476f
#define SQ6_INVf  0.4082482904638631f
#define SQ2_3f    0.816496580927726f
#define LOG2Ef    1.4426950408889634f

typedef __attribute__((ext_vector_type(8))) _Float16 half8;
typedef __attribute__((ext_vector_type(4))) float f32x4;

__device__ __forceinline__ float wave_sum(float v) {
#pragma unroll
  for (int off = 32; off > 0; off >>= 1) v += __shfl_xor(v, off, 64);
  return v;
}

__device__ __forceinline__ unsigned pkh(float a, float b) {
  auto h = __builtin_amdgcn_cvt_pkrtz(a, b);   // __fp16 ext_vector(2)
  return __builtin_bit_cast(unsigned, h);
}

// ---------------- Kernel A: per-atom precompute + pack (fused) --------------
// One wave per atom. Butterfly allreduce leaves r[0..33] in every lane;
// lanes 0..15 pack+write their f16 row (row offset = lane*8 halfs, matching
// the proven pack_m layout), lane 16 writes atomC.
// Row content (verified against round-7/8 pack_m):
//  0:[1]  1:[c0e]  2:[c0o]  3..5:[dip_i, Q row i]  6..8:[biv_i, O row i]
//  9:[qe_zz, le]  10:[qo_zz, lo]  11:zero  12:[qe_xx-qe_zz, qe_yy-qe_zz, A2e,A3e,A4e]
//  13: odd of 12   14: zero   15: pad
__global__ __launch_bounds__(256) void precompute_pack(
    const float* __restrict__ atom_coords, const float* __restrict__ alpha,
    const float* __restrict__ even_scalar, const float* __restrict__ odd_scalar,
    const float* __restrict__ odd_vector, const float* __restrict__ even_vector,
    const float* __restrict__ even_tensor, const float* __restrict__ odd_tensor,
    const float* __restrict__ W, const float* __restrict__ b,
    _Float16* __restrict__ Mh, float4* __restrict__ atomC)
{
  const int a = blockIdx.x * 4 + (threadIdx.x >> 6);
  const int d = threadIdx.x & 63;

  const float es  = even_scalar[a * DN + d];
  const float os  = odd_scalar[a * DN + d];
  const float ov0 = odd_vector[(a * DN + d) * 3 + 0];
  const float ov1 = odd_vector[(a * DN + d) * 3 + 1];
  const float ov2 = odd_vector[(a * DN + d) * 3 + 2];
  const float ev0 = even_vector[(a * DN + d) * 3 + 0];
  const float ev1 = even_vector[(a * DN + d) * 3 + 1];
  const float ev2 = even_vector[(a * DN + d) * 3 + 2];
  const float et0 = even_tensor[(a * DN + d) * 5 + 0];
  const float et1 = even_tensor[(a * DN + d) * 5 + 1];
  const float et2 = even_tensor[(a * DN + d) * 5 + 2];
  const float et3 = even_tensor[(a * DN + d) * 5 + 3];
  const float et4 = even_tensor[(a * DN + d) * 5 + 4];
  const float ot0 = odd_tensor[(a * DN + d) * 5 + 0];
  const float ot1 = odd_tensor[(a * DN + d) * 5 + 1];
  const float ot2 = odd_tensor[(a * DN + d) * 5 + 2];
  const float ot3 = odd_tensor[(a * DN + d) * 5 + 3];
  const float ot4 = odd_tensor[(a * DN + d) * 5 + 4];

  const float w0 = W[0 * DN + d];
  const float w1 = W[1 * DN + d];
  const float w2 = W[2 * DN + d];
  const float w3 = W[3 * DN + d];
  const float w4 = W[4 * DN + d];
  const float w5 = W[5 * DN + d];
  const float w6 = W[6 * DN + d];
  const float w7 = W[7 * DN + d];
  const float w8 = W[8 * DN + d];
  const float w9 = W[9 * DN + d];

  float r[34];
  r[0]  = es * w0;
  r[1]  = os * w1;
  r[2]  = ov0 * w2; r[3]  = ov1 * w2; r[4]  = ov2 * w2;
  r[5]  = ev0 * w3; r[6]  = ev1 * w3; r[7]  = ev2 * w3;
  r[8]  = et0 * w4; r[9]  = et1 * w4; r[10] = et2 * w4; r[11] = et3 * w4; r[12] = et4 * w4;
  r[13] = ot0 * w5; r[14] = ot1 * w5; r[15] = ot2 * w5; r[16] = ot3 * w5; r[17] = ot4 * w5;
  r[18] = ov0 * w6; r[19] = ov1 * w6; r[20] = ov2 * w6;
  r[21] = ev0 * w7; r[22] = ev1 * w7; r[23] = ev2 * w7;
  r[24] = et0 * w8; r[25] = et1 * w8; r[26] = et2 * w8; r[27] = et3 * w8; r[28] = et4 * w8;
  r[29] = ot0 * w9; r[30] = ot1 * w9; r[31] = ot2 * w9; r[32] = ot3 * w9; r[33] = ot4 * w9;

#pragma unroll
  for (int k = 0; k < 34; ++k) r[k] = wave_sum(r[k]);

  if (d < 16) {
    // even quadrupole (coeffs + b4)
    const float eb = b[4];
    const float ec0 = r[8] + eb, ec1 = r[9] + eb, ec2 = r[10] + eb,
                ec3 = r[11] + eb, ec4 = r[12] + eb;
    const float Qzz = ec1 * SQ2_3f;
    const float Qxx = 0.5f * (ec0 * SQ2f - Qzz);
    const float Qyy = 0.5f * (-ec0 * SQ2f - Qzz);
    const float Qxy = ec2 * INV_SQ2f, Qxz = ec3 * INV_SQ2f, Qyz = ec4 * INV_SQ2f;
    // odd quadrupole (coeffs + b5)
    const float ob = b[5];
    const float oc0 = r[13] + ob, oc1 = r[14] + ob, oc2 = r[15] + ob,
                oc3 = r[16] + ob, oc4 = r[17] + ob;
    const float Ozz = oc1 * SQ2_3f;
    const float Oxx = 0.5f * (oc0 * SQ2f - Ozz);
    const float Oyy = 0.5f * (-oc0 * SQ2f - Ozz);
    const float Oxy = oc2 * INV_SQ2f, Oxz = oc3 * INV_SQ2f, Oyz = oc4 * INV_SQ2f;
    // angular quad coeffs
    const float A0e = r[24] * INV_SQ2f, A1e = r[25] * SQ6_INVf;
    const float A2e = r[26] * SQ2f, A3e = r[27] * SQ2f, A4e = r[28] * SQ2f;
    const float qe_xx = A0e - A1e, qe_yy = -A0e - A1e, qe_zz = 2.0f * A1e;
    const float A0o = r[29] * INV_SQ2f, A1o = r[30] * SQ6_INVf;
    const float A2o = r[31] * SQ2f, A3o = r[32] * SQ2f, A4o = r[33] * SQ2f;
    const float qo_xx = A0o - A1o, qo_yy = -A0o - A1o, qo_zz = 2.0f * A1o;

    float m[8];
#pragma unroll
    for (int k = 0; k < 8; ++k) m[k] = 0.f;
    switch (d) {
      case 0:  m[0] = 1.f; break;
      case 1:  m[0] = r[0] + b[0]; break;
      case 2:  m[0] = r[1] + b[1]; break;
      case 3:  m[0]=r[2]+b[2]; m[1]=Qxx; m[2]=Qxy; m[3]=Qxz; break;
      case 4:  m[0]=r[3]+b[2]; m[1]=Qxy; m[2]=Qyy; m[3]=Qyz; break;
      case 5:  m[0]=r[4]+b[2]; m[1]=Qxz; m[2]=Qyz; m[3]=Qzz; break;
      case 6:  m[0]=r[5]+b[3]; m[1]=Oxx; m[2]=Oxy; m[3]=Oxz; break;
      case 7:  m[0]=r[6]+b[3]; m[1]=Oxy; m[2]=Oyy; m[3]=Oyz; break;
      case 8:  m[0]=r[7]+b[3]; m[1]=Oxz; m[2]=Oyz; m[3]=Ozz; break;
      case 9:  m[0]=qe_zz; m[1]=r[18]; m[2]=r[19]; m[3]=r[20]; break;
      case 10: m[0]=qo_zz; m[1]=r[21]; m[2]=r[22]; m[3]=r[23]; break;
      case 12: m[0]=qe_xx-qe_zz; m[1]=qe_yy-qe_zz;
               m[2]=A2e; m[3]=A3e; m[4]=A4e; break;
      case 13: m[0]=qo_xx-qo_zz; m[1]=qo_yy-qo_zz;
               m[2]=A2o; m[3]=A3o; m[4]=A4o; break;
      default: break;   // rows 11, 14, 15 stay zero
    }
    union { unsigned u[4]; half8 h; } row;
    row.u[0] = pkh(m[0], m[1]);
    row.u[1] = pkh(m[2], m[3]);
    row.u[2] = pkh(m[4], m[5]);
    row.u[3] = pkh(m[6], m[7]);
    *(half8*)(Mh + (size_t)a * AH + d * 8) = row.h;
  } else if (d == 16) {
    atomC[a] = make_float4(atom_coords[a * 3 + 0], atom_coords[a * 3 + 1],
                           atom_coords[a * 3 + 2], -alpha[a] * LOG2Ef);
  }
}

// ---------------- Kernel B: MFMA splat (unchanged, proven round 8) ----------
__global__ __launch_bounds__(256, 4) void mfma_splat(
    const float* __restrict__ qcoord, const _Float16* __restrict__ Mh,
    const float4* __restrict__ atomC, float* __restrict__ P)
{
  __shared__ __align__(16) _Float16 smM[CHUNK * AH];
  __shared__ float4 smC[CHUNK];
  const int tid = threadIdx.x;
  const int abase = blockIdx.y * CHUNK;

  {
    const float4* src = (const float4*)(Mh + (size_t)abase * AH);
    float4* dst = (float4*)smM;
#pragma unroll
    for (int t = 0; t < 4; ++t) dst[tid + t * 256] = src[tid + t * 256];
    if (tid < 64) dst[1024 + tid] = src[1024 + tid];
  }
  if (tid < CHUNK) smC[tid] = atomC[abase + tid];

  const int lane = tid & 63;
  const int wid = tid >> 6;
  const int fq = lane & 15;
  const int g = (lane >> 4) & 3;
  const int qb = blockIdx.x * 256 + wid * 64;

  float qx[4], qy[4], qz[4];
#pragma unroll
  for (int jt = 0; jt < 4; ++jt) {
    const int q = qb + jt * 16 + fq;
    qx[jt] = qcoord[q * 3 + 0];
    qy[jt] = qcoord[q * 3 + 1];
    qz[jt] = qcoord[q * 3 + 2];
  }

  const int a1off = (fq < 11 ? fq : 11) * 8;
  const int a2off = 96 + (fq == 9 ? 0 : (fq == 10 ? 8 : 16));
  const _Float16* p1 = smM + g * AH + a1off;
  const _Float16* p2 = smM + g * AH + a2off;

  __syncthreads();

  f32x4 acc[4];
#pragma unroll
  for (int jt = 0; jt < 4; ++jt) acc[jt] = (f32x4){0.f, 0.f, 0.f, 0.f};

  for (int it = 0; it < CHUNK / 4; ++it) {
    const half8 a1 = *(const half8*)(p1 + it * (4 * AH));
    const half8 a2 = *(const half8*)(p2 + it * (4 * AH));
    const float4 ca = smC[it * 4 + g];

#pragma unroll
    for (int jt = 0; jt < 4; ++jt) {
      const float dx = qx[jt] - ca.x, dy = qy[jt] - ca.y, dz = qz[jt] - ca.z;
      const float d2 = fmaf(dx, dx, fmaf(dy, dy, dz * dz));
      const float w = __builtin_amdgcn_exp2f(ca.w * d2);
      const float inv = __builtin_amdgcn_rsqf(d2);
      const float g1 = w * inv;
      const float g2 = g1 * inv;
      const float m1 = g1 * dx, m2 = g1 * dy, m3 = g1 * dz;
      const float t = g2 * dx, u = g2 * dy;
      const float m4 = t * dx, m6 = t * dy, m7 = t * dz;
      const float m5 = u * dy, m8 = u * dz;

      union { unsigned uu[4]; half8 h; } b1, b2;
      b1.uu[0] = pkh(w, m1);   b1.uu[1] = pkh(m2, m3);
      b1.uu[2] = 0u;           b1.uu[3] = 0u;
      b2.uu[0] = pkh(m4, m5);  b2.uu[1] = pkh(m6, m7);
      b2.uu[2] = pkh(m8, 0.f); b2.uu[3] = 0u;

      acc[jt] = __builtin_amdgcn_mfma_f32_16x16x32_f16(a1, b1.h, acc[jt], 0, 0, 0);
      acc[jt] = __builtin_amdgcn_mfma_f32_16x16x32_f16(a2, b2.h, acc[jt], 0, 0, 0);
    }
  }

  const int frow = (lane >> 4) * 4;
#pragma unroll
  for (int jt = 0; jt < 4; ++jt) {
    float* Pb = P + (size_t)blockIdx.y * 16 * QN + qb + jt * 16 + fq;
#pragma unroll
    for (int r = 0; r < 4; ++r) {
      const int f = frow + r;
      if (f < 11) Pb[(size_t)f * QN] = acc[jt][r];
    }
  }
}

// ---------------- Kernel C: split-parallel reduce + finalize ----------------
// 256 blocks; block = 32 queries x 8 split-groups of 4. LDS combine.
__global__ __launch_bounds__(256) void reduce_combine(
    const float* __restrict__ P, const float* __restrict__ b,
    float* __restrict__ out)
{
  __shared__ float sm[11][8][32];
  const int tid = threadIdx.x;
  const int ql = tid & 31;
  const int sg = tid >> 5;            // 0..7
  const int q = blockIdx.x * 32 + ql;

  float acc[11];
#pragma unroll
  for (int f = 0; f < 11; ++f) acc[f] = 0.f;
#pragma unroll
  for (int j = 0; j < 4; ++j) {
    const int s = sg * 4 + j;
    const float* Ps = P + (size_t)s * 16 * QN + q;
#pragma unroll
    for (int f = 0; f < 11; ++f) acc[f] += Ps[(size_t)f * QN];
  }
#pragma unroll
  for (int f = 0; f < 11; ++f) sm[f][sg][ql] = acc[f];
  __syncthreads();

  if (tid < 32) {
    float a[11];
#pragma unroll
    for (int f = 0; f < 11; ++f) {
      float v = 0.f;
#pragma unroll
      for (int s = 0; s < 8; ++s) v += sm[f][s][tid];
      a[f] = v;
    }
    const int qq = blockIdx.x * 32 + tid;
    const float b_ea = b[6] + b[8];
    const float b_oa = b[7] + b[9];

    const float Sw = fmaxf(a[0], 1e-8f);
    const float inv = 1.0f / Sw;
    const float snw = a[0] * inv;
    const float scal = a[1] * inv;
    const float pse  = a[2] * inv;
    const float vx = a[3] * inv;
    const float vy = a[4] * inv;
    const float vz = a[5] * inv;
    const float bx = a[6] * inv;
    const float by = a[7] * inv;
    const float bz = a[8] * inv;
    const float ea = fmaf(b_ea, snw, a[9] * inv);
    const float oa = fmaf(b_oa, snw, a[10] * inv);

    const float evenc = scal + ea;
    const float oddc  = pse + oa;
    const float vn = sqrtf(fmaf(vx, vx, fmaf(vy, vy, vz * vz)));
    const float bn = sqrtf(fmaf(bx, bx, fmaf(by, by, bz * bz)));
    const float total = evenc + oddc + 0.1f * vn + 0.05f * bn;

    out[qq] = total;
    out[QN + qq] = evenc;
    out[2 * QN + qq] = oddc;
    float* mv = out + 3 * QN + (size_t)qq * 16;
    mv[0] = scal;
    mv[1] = vx; mv[2] = vy; mv[3] = vz;
    mv[4] = 0.f;
    mv[5] = bz; mv[6] = -by; mv[7] = bx;
    mv[8] = 0.f; mv[9] = 0.f; mv[10] = 0.f;
    mv[11] = pse;
    mv[12] = 0.f; mv[13] = 0.f; mv[14] = 0.f; mv[15] = 0.f;
  }
}

extern "C" void kernel_launch(void* const* d_in, const int* in_sizes, int n_in,
                              void* d_out, int out_size, void* d_ws, size_t ws_size,
                              hipStream_t stream) {
  const float* query_coords = (const float*)d_in[0];
  const float* atom_coords  = (const float*)d_in[1];
  const float* alpha        = (const float*)d_in[2];
  const float* even_scalar  = (const float*)d_in[3];
  const float* odd_scalar   = (const float*)d_in[4];
  const float* odd_vector   = (const float*)d_in[5];
  const float* even_vector  = (const float*)d_in[6];
  const float* even_tensor  = (const float*)d_in[7];
  const float* odd_tensor   = (const float*)d_in[8];
  const float* W            = (const float*)d_in[9];
  const float* b            = (const float*)d_in[10];
  float* out = (float*)d_out;

  const size_t mhBytes = (size_t)AN * AH * sizeof(_Float16);        // 557056
  char* ws = (char*)d_ws;
  _Float16*  Mh     = (_Float16*)ws;
  float4*    atomCp = (float4*)(ws + mhBytes);
  float*     P      = (float*)(ws + mhBytes + (size_t)AN * sizeof(float4));

  precompute_pack<<<AN / 4, 256, 0, stream>>>(
      atom_coords, alpha, even_scalar, odd_scalar, odd_vector, even_vector,
      even_tensor, odd_tensor, W, b, Mh, atomCp);
  mfma_splat<<<dim3(QN / 256, NSPLIT), 256, 0, stream>>>(
      query_coords, Mh, atomCp, P);
  reduce_combine<<<QN / 32, 256, 0, stream>>>(P, b, out);
}

// Round 10
// 30.795 us; speedup vs baseline: 2.6273x; 1.1974x over previous
//
#include <hip/hip_runtime.h>
#include <math.h>

#define QN 8192
#define AN 2048
#define DN 64
#define NSPLIT 32
#define CHUNK 64        // atoms per block in mfma_splat
#define AH 136          // halfs per atom in packed M (17 float4)
#define NQ 2            // q-tiles of 16 per wave

#define SQ2f      1.4142135623730951f
#define INV_SQ2f  0.7071067811865476f
#define SQ6_INVf  0.4082482904638631f
#define SQ2_3f    0.816496580927726f
#define LOG2Ef    1.4426950408889634f

typedef __attribute__((ext_vector_type(8))) _Float16 half8;
typedef __attribute__((ext_vector_type(4))) float f32x4;

__device__ __forceinline__ float wave_sum(float v) {
#pragma unroll
  for (int off = 32; off > 0; off >>= 1) v += __shfl_xor(v, off, 64);
  return v;
}

__device__ __forceinline__ unsigned pkh(float a, float b) {
  auto h = __builtin_amdgcn_cvt_pkrtz(a, b);   // __fp16 ext_vector(2)
  return __builtin_bit_cast(unsigned, h);
}

// ---------------- Kernel A: per-atom precompute + pack + Acc zeroing --------
// One wave per atom (proven round 9). Also zeroes the 11*QN atomic accumulator.
__global__ __launch_bounds__(256) void precompute_pack(
    const float* __restrict__ atom_coords, const float* __restrict__ alpha,
    const float* __restrict__ even_scalar, const float* __restrict__ odd_scalar,
    const float* __restrict__ odd_vector, const float* __restrict__ even_vector,
    const float* __restrict__ even_tensor, const float* __restrict__ odd_tensor,
    const float* __restrict__ W, const float* __restrict__ b,
    _Float16* __restrict__ Mh, float4* __restrict__ atomC,
    float* __restrict__ Acc)
{
  // zero the atomic accumulator (512 blocks x 256 threads >= 11*QN)
  {
    const int zi = blockIdx.x * 256 + threadIdx.x;
    if (zi < 11 * QN) Acc[zi] = 0.f;
  }

  const int a = blockIdx.x * 4 + (threadIdx.x >> 6);
  const int d = threadIdx.x & 63;

  const float es  = even_scalar[a * DN + d];
  const float os  = odd_scalar[a * DN + d];
  const float ov0 = odd_vector[(a * DN + d) * 3 + 0];
  const float ov1 = odd_vector[(a * DN + d) * 3 + 1];
  const float ov2 = odd_vector[(a * DN + d) * 3 + 2];
  const float ev0 = even_vector[(a * DN + d) * 3 + 0];
  const float ev1 = even_vector[(a * DN + d) * 3 + 1];
  const float ev2 = even_vector[(a * DN + d) * 3 + 2];
  const float et0 = even_tensor[(a * DN + d) * 5 + 0];
  const float et1 = even_tensor[(a * DN + d) * 5 + 1];
  const float et2 = even_tensor[(a * DN + d) * 5 + 2];
  const float et3 = even_tensor[(a * DN + d) * 5 + 3];
  const float et4 = even_tensor[(a * DN + d) * 5 + 4];
  const float ot0 = odd_tensor[(a * DN + d) * 5 + 0];
  const float ot1 = odd_tensor[(a * DN + d) * 5 + 1];
  const float ot2 = odd_tensor[(a * DN + d) * 5 + 2];
  const float ot3 = odd_tensor[(a * DN + d) * 5 + 3];
  const float ot4 = odd_tensor[(a * DN + d) * 5 + 4];

  const float w0 = W[0 * DN + d];
  const float w1 = W[1 * DN + d];
  const float w2 = W[2 * DN + d];
  const float w3 = W[3 * DN + d];
  const float w4 = W[4 * DN + d];
  const float w5 = W[5 * DN + d];
  const float w6 = W[6 * DN + d];
  const float w7 = W[7 * DN + d];
  const float w8 = W[8 * DN + d];
  const float w9 = W[9 * DN + d];

  float r[34];
  r[0]  = es * w0;
  r[1]  = os * w1;
  r[2]  = ov0 * w2; r[3]  = ov1 * w2; r[4]  = ov2 * w2;
  r[5]  = ev0 * w3; r[6]  = ev1 * w3; r[7]  = ev2 * w3;
  r[8]  = et0 * w4; r[9]  = et1 * w4; r[10] = et2 * w4; r[11] = et3 * w4; r[12] = et4 * w4;
  r[13] = ot0 * w5; r[14] = ot1 * w5; r[15] = ot2 * w5; r[16] = ot3 * w5; r[17] = ot4 * w5;
  r[18] = ov0 * w6; r[19] = ov1 * w6; r[20] = ov2 * w6;
  r[21] = ev0 * w7; r[22] = ev1 * w7; r[23] = ev2 * w7;
  r[24] = et0 * w8; r[25] = et1 * w8; r[26] = et2 * w8; r[27] = et3 * w8; r[28] = et4 * w8;
  r[29] = ot0 * w9; r[30] = ot1 * w9; r[31] = ot2 * w9; r[32] = ot3 * w9; r[33] = ot4 * w9;

#pragma unroll
  for (int k = 0; k < 34; ++k) r[k] = wave_sum(r[k]);

  if (d < 16) {
    const float eb = b[4];
    const float ec0 = r[8] + eb, ec1 = r[9] + eb, ec2 = r[10] + eb,
                ec3 = r[11] + eb, ec4 = r[12] + eb;
    const float Qzz = ec1 * SQ2_3f;
    const float Qxx = 0.5f * (ec0 * SQ2f - Qzz);
    const float Qyy = 0.5f * (-ec0 * SQ2f - Qzz);
    const float Qxy = ec2 * INV_SQ2f, Qxz = ec3 * INV_SQ2f, Qyz = ec4 * INV_SQ2f;
    const float ob = b[5];
    const float oc0 = r[13] + ob, oc1 = r[14] + ob, oc2 = r[15] + ob,
                oc3 = r[16] + ob, oc4 = r[17] + ob;
    const float Ozz = oc1 * SQ2_3f;
    const float Oxx = 0.5f * (oc0 * SQ2f - Ozz);
    const float Oyy = 0.5f * (-oc0 * SQ2f - Ozz);
    const float Oxy = oc2 * INV_SQ2f, Oxz = oc3 * INV_SQ2f, Oyz = oc4 * INV_SQ2f;
    const float A0e = r[24] * INV_SQ2f, A1e = r[25] * SQ6_INVf;
    const float A2e = r[26] * SQ2f, A3e = r[27] * SQ2f, A4e = r[28] * SQ2f;
    const float qe_xx = A0e - A1e, qe_yy = -A0e - A1e, qe_zz = 2.0f * A1e;
    const float A0o = r[29] * INV_SQ2f, A1o = r[30] * SQ6_INVf;
    const float A2o = r[31] * SQ2f, A3o = r[32] * SQ2f, A4o = r[33] * SQ2f;
    const float qo_xx = A0o - A1o, qo_yy = -A0o - A1o, qo_zz = 2.0f * A1o;

    float m[8];
#pragma unroll
    for (int k = 0; k < 8; ++k) m[k] = 0.f;
    switch (d) {
      case 0:  m[0] = 1.f; break;
      case 1:  m[0] = r[0] + b[0]; break;
      case 2:  m[0] = r[1] + b[1]; break;
      case 3:  m[0]=r[2]+b[2]; m[1]=Qxx; m[2]=Qxy; m[3]=Qxz; break;
      case 4:  m[0]=r[3]+b[2]; m[1]=Qxy; m[2]=Qyy; m[3]=Qyz; break;
      case 5:  m[0]=r[4]+b[2]; m[1]=Qxz; m[2]=Qyz; m[3]=Qzz; break;
      case 6:  m[0]=r[5]+b[3]; m[1]=Oxx; m[2]=Oxy; m[3]=Oxz; break;
      case 7:  m[0]=r[6]+b[3]; m[1]=Oxy; m[2]=Oyy; m[3]=Oyz; break;
      case 8:  m[0]=r[7]+b[3]; m[1]=Oxz; m[2]=Oyz; m[3]=Ozz; break;
      case 9:  m[0]=qe_zz; m[1]=r[18]; m[2]=r[19]; m[3]=r[20]; break;
      case 10: m[0]=qo_zz; m[1]=r[21]; m[2]=r[22]; m[3]=r[23]; break;
      case 12: m[0]=qe_xx-qe_zz; m[1]=qe_yy-qe_zz;
               m[2]=A2e; m[3]=A3e; m[4]=A4e; break;
      case 13: m[0]=qo_xx-qo_zz; m[1]=qo_yy-qo_zz;
               m[2]=A2o; m[3]=A3o; m[4]=A4o; break;
      default: break;   // rows 11, 14, 15 stay zero
    }
    union { unsigned u[4]; half8 h; } row;
    row.u[0] = pkh(m[0], m[1]);
    row.u[1] = pkh(m[2], m[3]);
    row.u[2] = pkh(m[4], m[5]);
    row.u[3] = pkh(m[6], m[7]);
    *(half8*)(Mh + (size_t)a * AH + d * 8) = row.h;
  } else if (d == 16) {
    atomC[a] = make_float4(atom_coords[a * 3 + 0], atom_coords[a * 3 + 1],
                           atom_coords[a * 3 + 2], -alpha[a] * LOG2Ef);
  }
}

// ---------------- Kernel B: MFMA splat, NQ=2, atomic accumulate -------------
// Per wave: 32 queries (2 q-tiles of 16) x 16 fields; grid (64, 32) = 2048
// blocks. Body and fragment layouts byte-for-byte from proven round 9.
__global__ __launch_bounds__(256, 6) void mfma_splat(
    const float* __restrict__ qcoord, const _Float16* __restrict__ Mh,
    const float4* __restrict__ atomC, float* __restrict__ Acc)
{
  __shared__ __align__(16) _Float16 smM[CHUNK * AH];
  __shared__ float4 smC[CHUNK];
  const int tid = threadIdx.x;
  const int abase = blockIdx.y * CHUNK;

  {
    const float4* src = (const float4*)(Mh + (size_t)abase * AH);
    float4* dst = (float4*)smM;
#pragma unroll
    for (int t = 0; t < 4; ++t) dst[tid + t * 256] = src[tid + t * 256];
    if (tid < 64) dst[1024 + tid] = src[1024 + tid];
  }
  if (tid < CHUNK) smC[tid] = atomC[abase + tid];

  const int lane = tid & 63;
  const int wid = tid >> 6;
  const int fq = lane & 15;
  const int g = (lane >> 4) & 3;
  const int qb = blockIdx.x * 128 + wid * 32;

  float qx[NQ], qy[NQ], qz[NQ];
#pragma unroll
  for (int jt = 0; jt < NQ; ++jt) {
    const int q = qb + jt * 16 + fq;
    qx[jt] = qcoord[q * 3 + 0];
    qy[jt] = qcoord[q * 3 + 1];
    qz[jt] = qcoord[q * 3 + 2];
  }

  const int a1off = (fq < 11 ? fq : 11) * 8;
  const int a2off = 96 + (fq == 9 ? 0 : (fq == 10 ? 8 : 16));
  const _Float16* p1 = smM + g * AH + a1off;
  const _Float16* p2 = smM + g * AH + a2off;

  __syncthreads();

  f32x4 acc[NQ];
#pragma unroll
  for (int jt = 0; jt < NQ; ++jt) acc[jt] = (f32x4){0.f, 0.f, 0.f, 0.f};

  for (int it = 0; it < CHUNK / 4; ++it) {
    const half8 a1 = *(const half8*)(p1 + it * (4 * AH));
    const half8 a2 = *(const half8*)(p2 + it * (4 * AH));
    const float4 ca = smC[it * 4 + g];

#pragma unroll
    for (int jt = 0; jt < NQ; ++jt) {
      const float dx = qx[jt] - ca.x, dy = qy[jt] - ca.y, dz = qz[jt] - ca.z;
      const float d2 = fmaf(dx, dx, fmaf(dy, dy, dz * dz));
      const float w = __builtin_amdgcn_exp2f(ca.w * d2);
      const float inv = __builtin_amdgcn_rsqf(d2);
      const float g1 = w * inv;
      const float g2 = g1 * inv;
      const float m1 = g1 * dx, m2 = g1 * dy, m3 = g1 * dz;
      const float t = g2 * dx, u = g2 * dy;
      const float m4 = t * dx, m6 = t * dy, m7 = t * dz;
      const float m5 = u * dy, m8 = u * dz;

      union { unsigned uu[4]; half8 h; } b1, b2;
      b1.uu[0] = pkh(w, m1);   b1.uu[1] = pkh(m2, m3);
      b1.uu[2] = 0u;           b1.uu[3] = 0u;
      b2.uu[0] = pkh(m4, m5);  b2.uu[1] = pkh(m6, m7);
      b2.uu[2] = pkh(m8, 0.f); b2.uu[3] = 0u;

      acc[jt] = __builtin_amdgcn_mfma_f32_16x16x32_f16(a1, b1.h, acc[jt], 0, 0, 0);
      acc[jt] = __builtin_amdgcn_mfma_f32_16x16x32_f16(a2, b2.h, acc[jt], 0, 0, 0);
    }
  }

  const int frow = (lane >> 4) * 4;
#pragma unroll
  for (int jt = 0; jt < NQ; ++jt) {
    const int q = qb + jt * 16 + fq;
#pragma unroll
    for (int r = 0; r < 4; ++r) {
      const int f = frow + r;
      if (f < 11) atomicAdd(&Acc[(size_t)f * QN + q], acc[jt][r]);
    }
  }
}

// ---------------- Kernel C: finalize from Acc[11][QN] -----------------------
__global__ __launch_bounds__(256) void finalize(
    const float* __restrict__ Acc, const float* __restrict__ b,
    float* __restrict__ out)
{
  const int q = blockIdx.x * 256 + threadIdx.x;
  float a[11];
#pragma unroll
  for (int f = 0; f < 11; ++f) a[f] = Acc[(size_t)f * QN + q];

  const float b_ea = b[6] + b[8];
  const float b_oa = b[7] + b[9];

  const float Sw = fmaxf(a[0], 1e-8f);
  const float inv = 1.0f / Sw;
  const float snw = a[0] * inv;
  const float scal = a[1] * inv;
  const float pse  = a[2] * inv;
  const float vx = a[3] * inv;
  const float vy = a[4] * inv;
  const float vz = a[5] * inv;
  const float bx = a[6] * inv;
  const float by = a[7] * inv;
  const float bz = a[8] * inv;
  const float ea = fmaf(b_ea, snw, a[9] * inv);
  const float oa = fmaf(b_oa, snw, a[10] * inv);

  const float evenc = scal + ea;
  const float oddc  = pse + oa;
  const float vn = sqrtf(fmaf(vx, vx, fmaf(vy, vy, vz * vz)));
  const float bn = sqrtf(fmaf(bx, bx, fmaf(by, by, bz * bz)));
  const float total = evenc + oddc + 0.1f * vn + 0.05f * bn;

  out[q] = total;
  out[QN + q] = evenc;
  out[2 * QN + q] = oddc;
  float* mv = out + 3 * QN + (size_t)q * 16;
  mv[0] = scal;
  mv[1] = vx; mv[2] = vy; mv[3] = vz;
  mv[4] = 0.f;
  mv[5] = bz; mv[6] = -by; mv[7] = bx;
  mv[8] = 0.f; mv[9] = 0.f; mv[10] = 0.f;
  mv[11] = pse;
  mv[12] = 0.f; mv[13] = 0.f; mv[14] = 0.f; mv[15] = 0.f;
}

extern "C" void kernel_launch(void* const* d_in, const int* in_sizes, int n_in,
                              void* d_out, int out_size, void* d_ws, size_t ws_size,
                              hipStream_t stream) {
  const float* query_coords = (const float*)d_in[0];
  const float* atom_coords  = (const float*)d_in[1];
  const float* alpha        = (const float*)d_in[2];
  const float* even_scalar  = (const float*)d_in[3];
  const float* odd_scalar   = (const float*)d_in[4];
  const float* odd_vector   = (const float*)d_in[5];
  const float* even_vector  = (const float*)d_in[6];
  const float* even_tensor  = (const float*)d_in[7];
  const float* odd_tensor   = (const float*)d_in[8];
  const float* W            = (const float*)d_in[9];
  const float* b            = (const float*)d_in[10];
  float* out = (float*)d_out;

  const size_t mhBytes = (size_t)AN * AH * sizeof(_Float16);        // 557056
  char* ws = (char*)d_ws;
  _Float16*  Mh     = (_Float16*)ws;
  float4*    atomCp = (float4*)(ws + mhBytes);
  float*     Acc    = (float*)(ws + mhBytes + (size_t)AN * sizeof(float4));

  precompute_pack<<<AN / 4, 256, 0, stream>>>(
      atom_coords, alpha, even_scalar, odd_scalar, odd_vector, even_vector,
      even_tensor, odd_tensor, W, b, Mh, atomCp, Acc);
  mfma_splat<<<dim3(QN / 128, NSPLIT), 256, 0, stream>>>(
      query_coords, Mh, atomCp, Acc);
  finalize<<<QN / 256, 256, 0, stream>>>(Acc, b, out);
}